// Round 1
// baseline (679.920 us; speedup 1.0000x reference)
//
#include <hip/hip_runtime.h>
#include <hip/hip_bf16.h>

// GCN: 5 layers on fixed graph (N=100000, E=600000), fp32.
// Strategy:
//   - Build CSR (by target col) per launch: counts -> exclusive scan -> scatter fill.
//   - Propagate on the narrower side of each conv:  A_hat(X W) == (A_hat X) W.
//   - Aggregation = gather over incoming edges (deterministic, no atomics).
//   - GEMMs: fp32, W staged in LDS, 64 outputs/thread in registers, float4 loads.

#define NB 256  // default block

static __host__ __device__ inline int ceil_div(int a, int b) { return (a + b - 1) / b; }

// ---------------- CSR build ----------------

__global__ void k_zero(int* p, int n) {
    int i = blockIdx.x * NB + threadIdx.x;
    if (i < n) p[i] = 0;
}

__global__ void k_count(const int* __restrict__ col, int e, int* __restrict__ counts) {
    int i = blockIdx.x * NB + threadIdx.x;
    if (i < e) atomicAdd(&counts[col[i]], 1);
}

__global__ void k_dis(const int* __restrict__ counts, float* __restrict__ dis, int n) {
    int i = blockIdx.x * NB + threadIdx.x;
    if (i < n) dis[i] = rsqrtf((float)(counts[i] + 1));  // +1 self-loop
}

// exclusive scan, 3-kernel: per-block scan -> scan of block sums -> add offsets
__global__ void k_scan1(const int* __restrict__ counts, int n,
                        int* __restrict__ partial, int* __restrict__ blockSums) {
    __shared__ int s[NB];
    int i = blockIdx.x * NB + threadIdx.x;
    int v = (i < n) ? counts[i] : 0;
    s[threadIdx.x] = v;
    __syncthreads();
    for (int off = 1; off < NB; off <<= 1) {
        int t = (threadIdx.x >= off) ? s[threadIdx.x - off] : 0;
        __syncthreads();
        s[threadIdx.x] += t;
        __syncthreads();
    }
    if (i < n) partial[i] = s[threadIdx.x] - v;  // exclusive within block
    if (threadIdx.x == NB - 1) blockSums[blockIdx.x] = s[NB - 1];
}

__global__ void k_scan2(int* __restrict__ blockSums, int nb) {
    __shared__ int s[512];
    int v = (threadIdx.x < nb) ? blockSums[threadIdx.x] : 0;
    s[threadIdx.x] = v;
    __syncthreads();
    for (int off = 1; off < 512; off <<= 1) {
        int t = (threadIdx.x >= off) ? s[threadIdx.x - off] : 0;
        __syncthreads();
        s[threadIdx.x] += t;
        __syncthreads();
    }
    if (threadIdx.x < nb) blockSums[threadIdx.x] = s[threadIdx.x] - v;  // exclusive
}

__global__ void k_scan3(int* __restrict__ row_ptr, int* __restrict__ cursor,
                        const int* __restrict__ blockSums, int n, int e) {
    int i = blockIdx.x * NB + threadIdx.x;
    if (i < n) {
        int v = row_ptr[i] + blockSums[blockIdx.x];
        row_ptr[i] = v;
        cursor[i] = v;
    } else if (i == n) {
        row_ptr[n] = e;
    }
}

__global__ void k_fill(const int* __restrict__ row, const int* __restrict__ col, int e,
                       int* __restrict__ cursor, int* __restrict__ src_sorted,
                       float* __restrict__ nrm_sorted, const float* __restrict__ dis) {
    int i = blockIdx.x * NB + threadIdx.x;
    if (i < e) {
        int c = col[i], r = row[i];
        int pos = atomicAdd(&cursor[c], 1);
        src_sorted[pos] = r;
        nrm_sorted[pos] = dis[r] * dis[c];
    }
}

// ---------------- propagation (aggregation) ----------------

// width-3 input aggregation: S[i] = dis[i]^2 * x[i] + sum_e nrm*x[src]; stride-4 output
__global__ void k_agg3(const float* __restrict__ x, const int* __restrict__ row_ptr,
                       const int* __restrict__ src, const float* __restrict__ nrm,
                       const float* __restrict__ dis, float* __restrict__ S, int n) {
    int i = blockIdx.x * NB + threadIdx.x;
    if (i >= n) return;
    float d = dis[i], w = d * d;
    float a0 = w * x[3 * i], a1 = w * x[3 * i + 1], a2 = w * x[3 * i + 2];
    int s0 = row_ptr[i], s1 = row_ptr[i + 1];
    for (int e = s0; e < s1; ++e) {
        int j = src[e];
        float nv = nrm[e];
        a0 += nv * x[3 * j];
        a1 += nv * x[3 * j + 1];
        a2 += nv * x[3 * j + 2];
    }
    S[4 * i] = a0; S[4 * i + 1] = a1; S[4 * i + 2] = a2; S[4 * i + 3] = 0.f;
}

// width-F aggregation with bias (+optional relu). F threads per node, coalesced gathers.
template <int F, bool RELU>
__global__ __launch_bounds__(256) void k_agg(const float* __restrict__ Z,
                                             const float* __restrict__ bias,
                                             const int* __restrict__ row_ptr,
                                             const int* __restrict__ src,
                                             const float* __restrict__ nrm,
                                             const float* __restrict__ dis,
                                             float* __restrict__ Out, int n) {
    constexpr int NPB = 256 / F;
    int local = threadIdx.x / F;
    int f = threadIdx.x % F;
    int i = blockIdx.x * NPB + local;
    if (i >= n) return;
    float d = dis[i];
    float acc = d * d * Z[(size_t)i * F + f];
    int s0 = row_ptr[i], s1 = row_ptr[i + 1];
    for (int e = s0; e < s1; ++e) {
        int j = src[e];
        float nv = nrm[e];
        acc += nv * Z[(size_t)j * F + f];
    }
    acc += bias[f];
    if (RELU) acc = fmaxf(acc, 0.f);
    Out[(size_t)i * F + f] = acc;
}

// width-1 final aggregation (no relu)
__global__ void k_agg1(const float* __restrict__ z, const float* __restrict__ b5,
                       const int* __restrict__ row_ptr, const int* __restrict__ src,
                       const float* __restrict__ nrm, const float* __restrict__ dis,
                       float* __restrict__ out, int n) {
    int i = blockIdx.x * NB + threadIdx.x;
    if (i >= n) return;
    float d = dis[i];
    float acc = d * d * z[i];
    int s0 = row_ptr[i], s1 = row_ptr[i + 1];
    for (int e = s0; e < s1; ++e) acc += nrm[e] * z[src[e]];
    out[i] = acc + b5[0];
}

// ---------------- GEMMs ----------------

// Layer 1: H1 = relu(S @ W1 + b1), S is N x 4 (first 3 cols used), W1 is 3x128
__global__ __launch_bounds__(256) void k_l1(const float* __restrict__ S,
                                            const float* __restrict__ W1,
                                            const float* __restrict__ b1,
                                            float* __restrict__ A, int n) {
    __shared__ float w[3][128];
    __shared__ float bb[128];
    if (threadIdx.x < 128) {
        w[0][threadIdx.x] = W1[threadIdx.x];
        w[1][threadIdx.x] = W1[128 + threadIdx.x];
        w[2][threadIdx.x] = W1[256 + threadIdx.x];
        bb[threadIdx.x] = b1[threadIdx.x];
    }
    __syncthreads();
    int f = threadIdx.x & 127;
    int i = blockIdx.x * 2 + (threadIdx.x >> 7);
    if (i >= n) return;
    float4 xv = *(const float4*)&S[4 * i];
    float v = xv.x * w[0][f] + xv.y * w[1][f] + xv.z * w[2][f] + bb[f];
    A[(size_t)i * 128 + f] = fmaxf(v, 0.f);
}

// Z = H @ W  (H: n x K, W: K x F row-major). TPN threads per node, TF=F/TPN outputs each.
template <int K, int F, int TPN>
__global__ __launch_bounds__(256) void k_gemm(const float* __restrict__ H,
                                              const float* __restrict__ W,
                                              float* __restrict__ Z, int n) {
    constexpr int TF = F / TPN;
    constexpr int NPB = 256 / TPN;
    constexpr int KS = (K * F > 8192) ? 64 : K;  // stage <=32KB of W at a time
    __shared__ float w[KS * F];
    int node = blockIdx.x * NPB + threadIdx.x / TPN;
    bool valid = node < n;
    int nodec = valid ? node : (n - 1);
    int f0 = (threadIdx.x % TPN) * TF;
    const float* h = H + (size_t)nodec * K;
    float acc[TF];
#pragma unroll
    for (int j = 0; j < TF; ++j) acc[j] = 0.f;

    for (int s = 0; s < K; s += KS) {
        __syncthreads();
        for (int t = threadIdx.x; t < KS * F / 4; t += 256)
            ((float4*)w)[t] = ((const float4*)(W + (size_t)s * F))[t];
        __syncthreads();
#pragma unroll 1
        for (int k0 = 0; k0 < KS; k0 += 4) {
            float4 hv = *(const float4*)(h + s + k0);
#pragma unroll
            for (int kk = 0; kk < 4; ++kk) {
                float hk = (kk == 0) ? hv.x : (kk == 1) ? hv.y : (kk == 2) ? hv.z : hv.w;
                const float4* wr = (const float4*)&w[(k0 + kk) * F + f0];
#pragma unroll
                for (int j4 = 0; j4 < TF / 4; ++j4) {
                    float4 wv = wr[j4];
                    acc[4 * j4 + 0] += hk * wv.x;
                    acc[4 * j4 + 1] += hk * wv.y;
                    acc[4 * j4 + 2] += hk * wv.z;
                    acc[4 * j4 + 3] += hk * wv.w;
                }
            }
        }
    }
    if (valid) {
        float* zo = Z + (size_t)node * F + f0;
#pragma unroll
        for (int j4 = 0; j4 < TF / 4; ++j4)
            ((float4*)zo)[j4] = make_float4(acc[4 * j4], acc[4 * j4 + 1],
                                            acc[4 * j4 + 2], acc[4 * j4 + 3]);
    }
}

// z = H @ W5 (64 -> 1), thread per node
__global__ __launch_bounds__(256) void k_gemm5(const float* __restrict__ H,
                                               const float* __restrict__ W5,
                                               float* __restrict__ z, int n) {
    __shared__ float w[64];
    if (threadIdx.x < 64) w[threadIdx.x] = W5[threadIdx.x];
    __syncthreads();
    int i = blockIdx.x * NB + threadIdx.x;
    if (i >= n) return;
    const float4* h = (const float4*)&H[(size_t)i * 64];
    float acc = 0.f;
#pragma unroll
    for (int k = 0; k < 16; ++k) {
        float4 hv = h[k];
        acc += hv.x * w[4 * k] + hv.y * w[4 * k + 1] + hv.z * w[4 * k + 2] + hv.w * w[4 * k + 3];
    }
    z[i] = acc;
}

// ---------------- launch ----------------

static inline size_t align_up(size_t x) { return (x + 255) & ~(size_t)255; }

extern "C" void kernel_launch(void* const* d_in, const int* in_sizes, int n_in,
                              void* d_out, int out_size, void* d_ws, size_t ws_size,
                              hipStream_t stream) {
    const int n = in_sizes[0] / 3;   // 100000
    const int e = in_sizes[1] / 2;   // 600000

    const float* x   = (const float*)d_in[0];
    const int*   ei  = (const int*)d_in[1];
    const int*   row = ei;       // sources
    const int*   col = ei + e;   // targets
    const float* W1 = (const float*)d_in[2];  const float* b1 = (const float*)d_in[3];
    const float* W2 = (const float*)d_in[4];  const float* b2 = (const float*)d_in[5];
    const float* W3 = (const float*)d_in[6];  const float* b3 = (const float*)d_in[7];
    const float* W4 = (const float*)d_in[8];  const float* b4 = (const float*)d_in[9];
    const float* W5 = (const float*)d_in[10]; const float* b5 = (const float*)d_in[11];
    float* out = (float*)d_out;

    // workspace layout
    char* base = (char*)d_ws;
    size_t off = 0;
    auto alloc = [&](size_t bytes) { char* p = base + off; off = align_up(off + bytes); return p; };
    float* dis        = (float*)alloc((size_t)n * 4);
    int*   counts     = (int*)alloc((size_t)n * 4);
    int*   row_ptr    = (int*)alloc((size_t)(n + 1) * 4);
    int*   cursor     = (int*)alloc((size_t)n * 4);
    int*   blockSums  = (int*)alloc(1024 * 4);
    int*   src_sorted = (int*)alloc((size_t)e * 4);
    float* nrm_sorted = (float*)alloc((size_t)e * 4);
    float* S          = (float*)alloc((size_t)n * 4 * 4);
    float* A          = (float*)alloc((size_t)n * 128 * 4);
    float* B          = (float*)alloc((size_t)n * 128 * 4);
    (void)ws_size;

    const int gn = ceil_div(n, NB);       // 391
    const int ge = ceil_div(e, NB);       // 2344
    const int nb1 = gn;                    // scan block count (<=512 required)

    // --- CSR build ---
    k_zero<<<gn, NB, 0, stream>>>(counts, n);
    k_count<<<ge, NB, 0, stream>>>(col, e, counts);
    k_dis<<<gn, NB, 0, stream>>>(counts, dis, n);
    k_scan1<<<nb1, NB, 0, stream>>>(counts, n, row_ptr, blockSums);
    k_scan2<<<1, 512, 0, stream>>>(blockSums, nb1);
    k_scan3<<<ceil_div(n + 1, NB), NB, 0, stream>>>(row_ptr, cursor, blockSums, n, e);
    k_fill<<<ge, NB, 0, stream>>>(row, col, e, cursor, src_sorted, nrm_sorted, dis);

    // --- Layer 1: H1 = relu( (A_hat x) @ W1 + b1 ) ---
    k_agg3<<<gn, NB, 0, stream>>>(x, row_ptr, src_sorted, nrm_sorted, dis, S, n);
    k_l1<<<ceil_div(n, 2), 256, 0, stream>>>(S, W1, b1, A, n);

    // --- Layer 2: H2 = relu( A_hat(H1 @ W2) + b2 ) ---
    k_gemm<128, 128, 2><<<ceil_div(n, 128), 256, 0, stream>>>(A, W2, B, n);
    k_agg<128, true><<<ceil_div(n, 2), 256, 0, stream>>>(B, b2, row_ptr, src_sorted, nrm_sorted, dis, A, n);

    // --- Layer 3: H3 = relu( A_hat(H2 @ W3) + b3 ) ---
    k_gemm<128, 64, 1><<<ceil_div(n, 256), 256, 0, stream>>>(A, W3, B, n);
    k_agg<64, true><<<ceil_div(n, 4), 256, 0, stream>>>(B, b3, row_ptr, src_sorted, nrm_sorted, dis, A, n);

    // --- Layer 4: H4 = relu( A_hat(H3 @ W4) + b4 ) ---
    k_gemm<64, 64, 1><<<ceil_div(n, 256), 256, 0, stream>>>(A, W4, B, n);
    k_agg<64, true><<<ceil_div(n, 4), 256, 0, stream>>>(B, b4, row_ptr, src_sorted, nrm_sorted, dis, A, n);

    // --- Layer 5: out = A_hat(H4 @ W5) + b5 ---
    k_gemm5<<<gn, NB, 0, stream>>>(A, W5, B, n);   // B reused as z (n floats)
    k_agg1<<<gn, NB, 0, stream>>>(B, b5, row_ptr, src_sorted, nrm_sorted, dis, out, n);
}

// Round 2
// 442.556 us; speedup vs baseline: 1.5363x; 1.5363x over previous
//
#include <hip/hip_runtime.h>
#include <hip/hip_bf16.h>
#include <stdint.h>

// GCN 5-layer, N=100000, E=600000. bf16 pipeline:
//  - CSR build (counts -> scan -> fill) as before (fp32/int).
//  - GEMMs via mfma_f32_16x16x32_bf16, fp32 accum, weights pre-packed to
//    frag-contiguous layout (one b128 per lane per frag, no LDS).
//  - Activations stored bf16; aggregation gathers bf16, accumulates fp32.
//  - Threshold is 8 bf16 ulps of max|ref| => bf16 storage is in-budget.

#define NB 256

typedef __attribute__((ext_vector_type(8))) short bf16x8;
typedef __attribute__((ext_vector_type(4))) float f32x4;

static __host__ __device__ inline int ceil_div(int a, int b) { return (a + b - 1) / b; }

__device__ inline ushort f32_to_bf16(float x) {   // RNE
    uint32_t u = __float_as_uint(x);
    uint32_t r = (u + 0x7fffu + ((u >> 16) & 1u)) >> 16;
    return (ushort)r;
}
__device__ inline float bf16_lo(uint32_t u) { return __uint_as_float(u << 16); }
__device__ inline float bf16_hi(uint32_t u) { return __uint_as_float(u & 0xffff0000u); }
__device__ inline float bf16_to_f32(ushort h) { return __uint_as_float(((uint32_t)h) << 16); }

// ---------------- CSR build ----------------

__global__ void k_zero(int* p, int n) {
    int i = blockIdx.x * NB + threadIdx.x;
    if (i < n) p[i] = 0;
}

__global__ void k_count(const int* __restrict__ col, int e, int* __restrict__ counts) {
    int i = blockIdx.x * NB + threadIdx.x;
    if (i < e) atomicAdd(&counts[col[i]], 1);
}

__global__ void k_dis(const int* __restrict__ counts, float* __restrict__ dis, int n) {
    int i = blockIdx.x * NB + threadIdx.x;
    if (i < n) dis[i] = rsqrtf((float)(counts[i] + 1));  // +1 self-loop
}

__global__ void k_scan1(const int* __restrict__ counts, int n,
                        int* __restrict__ partial, int* __restrict__ blockSums) {
    __shared__ int s[NB];
    int i = blockIdx.x * NB + threadIdx.x;
    int v = (i < n) ? counts[i] : 0;
    s[threadIdx.x] = v;
    __syncthreads();
    for (int off = 1; off < NB; off <<= 1) {
        int t = (threadIdx.x >= off) ? s[threadIdx.x - off] : 0;
        __syncthreads();
        s[threadIdx.x] += t;
        __syncthreads();
    }
    if (i < n) partial[i] = s[threadIdx.x] - v;
    if (threadIdx.x == NB - 1) blockSums[blockIdx.x] = s[NB - 1];
}

__global__ void k_scan2(int* __restrict__ blockSums, int nb) {
    __shared__ int s[512];
    int v = (threadIdx.x < nb) ? blockSums[threadIdx.x] : 0;
    s[threadIdx.x] = v;
    __syncthreads();
    for (int off = 1; off < 512; off <<= 1) {
        int t = (threadIdx.x >= off) ? s[threadIdx.x - off] : 0;
        __syncthreads();
        s[threadIdx.x] += t;
        __syncthreads();
    }
    if (threadIdx.x < nb) blockSums[threadIdx.x] = s[threadIdx.x] - v;
}

__global__ void k_scan3(int* __restrict__ row_ptr, int* __restrict__ cursor,
                        const int* __restrict__ blockSums, int n, int e) {
    int i = blockIdx.x * NB + threadIdx.x;
    if (i < n) {
        int v = row_ptr[i] + blockSums[blockIdx.x];
        row_ptr[i] = v;
        cursor[i] = v;
    } else if (i == n) {
        row_ptr[n] = e;
    }
}

__global__ void k_fill(const int* __restrict__ row, const int* __restrict__ col, int e,
                       int* __restrict__ cursor, int* __restrict__ src_sorted,
                       float* __restrict__ nrm_sorted, const float* __restrict__ dis) {
    int i = blockIdx.x * NB + threadIdx.x;
    if (i < e) {
        int c = col[i], r = row[i];
        int pos = atomicAdd(&cursor[c], 1);
        src_sorted[pos] = r;
        nrm_sorted[pos] = dis[r] * dis[c];
    }
}

// ---------------- weight packing (fp32 -> bf16 frag layout) ----------------
// Wp[((t*KS+s)*64 + lane)*8 + j] = bf16(W[(s*32 + (lane>>4)*8 + j)*F + t*16 + (lane&15)])

template <int K, int F>
__global__ void k_pack(const float* __restrict__ W, ushort* __restrict__ Wp) {
    constexpr int KS = K / 32;
    int id = blockIdx.x * NB + threadIdx.x;
    if (id >= K * F) return;
    int j = id & 7;
    int lane = (id >> 3) & 63;
    int ts = id >> 9;
    int s = ts % KS;
    int t = ts / KS;
    int k = s * 32 + ((lane >> 4) << 3) + j;
    int f = t * 16 + (lane & 15);
    Wp[id] = f32_to_bf16(W[k * F + f]);
}

// ---------------- MFMA GEMM: Z = H @ W (bf16 in, bf16 out, fp32 accum) ----------------

template <int K, int F>
__global__ __launch_bounds__(256) void k_mmfma(const ushort* __restrict__ H,
                                               const ushort* __restrict__ Wp,
                                               ushort* __restrict__ Z, int n) {
    constexpr int KS = K / 32;   // k-steps of 32
    constexpr int FT = F / 16;   // 16-feature tiles
    int wid = threadIdx.x >> 6;
    int lane = threadIdx.x & 63;
    int node0 = blockIdx.x * 64 + wid * 16;
    int m = lane & 15;
    int quad = lane >> 4;
    int arow = node0 + m;
    if (arow >= n) arow = n - 1;  // clamped load, store masked below
    const bf16x8* aptr = (const bf16x8*)(H + (size_t)arow * K + quad * 8);
    bf16x8 a[KS];
#pragma unroll
    for (int s = 0; s < KS; ++s) a[s] = aptr[s * 4];  // k stride 32 elems = 4 x bf16x8
    const bf16x8* bp = (const bf16x8*)Wp;
#pragma unroll 2
    for (int t = 0; t < FT; ++t) {
        f32x4 acc = {0.f, 0.f, 0.f, 0.f};
#pragma unroll
        for (int s = 0; s < KS; ++s)
            acc = __builtin_amdgcn_mfma_f32_16x16x32_bf16(a[s], bp[(t * KS + s) * 64 + lane], acc, 0, 0, 0);
        int feat = t * 16 + m;
#pragma unroll
        for (int r = 0; r < 4; ++r) {
            int node = node0 + quad * 4 + r;
            if (node < n) Z[(size_t)node * F + feat] = f32_to_bf16(acc[r]);
        }
    }
}

// ---------------- aggregation (bf16 gather, fp32 accum) ----------------

// F=128: one wave per node, 2 features per lane (b32 gathers)
__global__ __launch_bounds__(256) void k_agg128(const ushort* __restrict__ Z,
                                                const float* __restrict__ bias,
                                                const int* __restrict__ row_ptr,
                                                const int* __restrict__ src,
                                                const float* __restrict__ nrm,
                                                const float* __restrict__ dis,
                                                ushort* __restrict__ Out, int n) {
    int lane = threadIdx.x & 63;
    int i = blockIdx.x * 4 + (threadIdx.x >> 6);
    if (i >= n) return;
    float d = dis[i], w = d * d;
    uint32_t u = *((const uint32_t*)(Z + (size_t)i * 128) + lane);
    float a0 = w * bf16_lo(u);
    float a1 = w * bf16_hi(u);
    int s0 = row_ptr[i], s1 = row_ptr[i + 1];
    for (int e = s0; e < s1; ++e) {
        int j = src[e];
        float nv = nrm[e];
        uint32_t v = *((const uint32_t*)(Z + (size_t)j * 128) + lane);
        a0 += nv * bf16_lo(v);
        a1 += nv * bf16_hi(v);
    }
    a0 = fmaxf(a0 + bias[2 * lane], 0.f);
    a1 = fmaxf(a1 + bias[2 * lane + 1], 0.f);
    uint32_t o = ((uint32_t)f32_to_bf16(a1) << 16) | (uint32_t)f32_to_bf16(a0);
    *((uint32_t*)(Out + (size_t)i * 128) + lane) = o;
}

// F=64: one wave per node, 1 feature per lane (b16 gathers)
__global__ __launch_bounds__(256) void k_agg64(const ushort* __restrict__ Z,
                                               const float* __restrict__ bias,
                                               const int* __restrict__ row_ptr,
                                               const int* __restrict__ src,
                                               const float* __restrict__ nrm,
                                               const float* __restrict__ dis,
                                               ushort* __restrict__ Out, int n) {
    int lane = threadIdx.x & 63;
    int i = blockIdx.x * 4 + (threadIdx.x >> 6);
    if (i >= n) return;
    float d = dis[i];
    float acc = d * d * bf16_to_f32(Z[(size_t)i * 64 + lane]);
    int s0 = row_ptr[i], s1 = row_ptr[i + 1];
    for (int e = s0; e < s1; ++e) {
        int j = src[e];
        float nv = nrm[e];
        acc += nv * bf16_to_f32(Z[(size_t)j * 64 + lane]);
    }
    acc = fmaxf(acc + bias[lane], 0.f);
    Out[(size_t)i * 64 + lane] = f32_to_bf16(acc);
}

// ---------------- layer 1 & layer 5 helpers ----------------

// width-3 input aggregation (fp32): S[i] = dis^2*x[i] + sum nrm*x[src]
__global__ void k_agg3(const float* __restrict__ x, const int* __restrict__ row_ptr,
                       const int* __restrict__ src, const float* __restrict__ nrm,
                       const float* __restrict__ dis, float* __restrict__ S, int n) {
    int i = blockIdx.x * NB + threadIdx.x;
    if (i >= n) return;
    float d = dis[i], w = d * d;
    float a0 = w * x[3 * i], a1 = w * x[3 * i + 1], a2 = w * x[3 * i + 2];
    int s0 = row_ptr[i], s1 = row_ptr[i + 1];
    for (int e = s0; e < s1; ++e) {
        int j = src[e];
        float nv = nrm[e];
        a0 += nv * x[3 * j];
        a1 += nv * x[3 * j + 1];
        a2 += nv * x[3 * j + 2];
    }
    S[4 * i] = a0; S[4 * i + 1] = a1; S[4 * i + 2] = a2; S[4 * i + 3] = 0.f;
}

// H1 = bf16(relu(S @ W1 + b1)), S: n x 4 (3 used), W1: 3x128 fp32
__global__ __launch_bounds__(256) void k_l1(const float* __restrict__ S,
                                            const float* __restrict__ W1,
                                            const float* __restrict__ b1,
                                            ushort* __restrict__ A, int n) {
    __shared__ float w[3][128];
    __shared__ float bb[128];
    if (threadIdx.x < 128) {
        w[0][threadIdx.x] = W1[threadIdx.x];
        w[1][threadIdx.x] = W1[128 + threadIdx.x];
        w[2][threadIdx.x] = W1[256 + threadIdx.x];
        bb[threadIdx.x] = b1[threadIdx.x];
    }
    __syncthreads();
    int f = threadIdx.x & 127;
    int i = blockIdx.x * 2 + (threadIdx.x >> 7);
    if (i >= n) return;
    float4 xv = *(const float4*)&S[4 * i];
    float v = xv.x * w[0][f] + xv.y * w[1][f] + xv.z * w[2][f] + bb[f];
    A[(size_t)i * 128 + f] = f32_to_bf16(fmaxf(v, 0.f));
}

// z = H(bf16, n x 64) @ W5(fp32 64x1), fp32 out
__global__ __launch_bounds__(256) void k_dot5(const ushort* __restrict__ H,
                                              const float* __restrict__ W5,
                                              float* __restrict__ z, int n) {
    __shared__ float w[64];
    if (threadIdx.x < 64) w[threadIdx.x] = W5[threadIdx.x];
    __syncthreads();
    int i = blockIdx.x * NB + threadIdx.x;
    if (i >= n) return;
    const uint32_t* h = (const uint32_t*)(H + (size_t)i * 64);
    float acc = 0.f;
#pragma unroll
    for (int k = 0; k < 32; ++k) {
        uint32_t u = h[k];
        acc += bf16_lo(u) * w[2 * k] + bf16_hi(u) * w[2 * k + 1];
    }
    z[i] = acc;
}

// width-1 final aggregation (fp32, no relu)
__global__ void k_agg1(const float* __restrict__ z, const float* __restrict__ b5,
                       const int* __restrict__ row_ptr, const int* __restrict__ src,
                       const float* __restrict__ nrm, const float* __restrict__ dis,
                       float* __restrict__ out, int n) {
    int i = blockIdx.x * NB + threadIdx.x;
    if (i >= n) return;
    float d = dis[i];
    float acc = d * d * z[i];
    int s0 = row_ptr[i], s1 = row_ptr[i + 1];
    for (int e = s0; e < s1; ++e) acc += nrm[e] * z[src[e]];
    out[i] = acc + b5[0];
}

// ---------------- launch ----------------

static inline size_t align_up(size_t x) { return (x + 255) & ~(size_t)255; }

extern "C" void kernel_launch(void* const* d_in, const int* in_sizes, int n_in,
                              void* d_out, int out_size, void* d_ws, size_t ws_size,
                              hipStream_t stream) {
    const int n = in_sizes[0] / 3;   // 100000
    const int e = in_sizes[1] / 2;   // 600000

    const float* x   = (const float*)d_in[0];
    const int*   ei  = (const int*)d_in[1];
    const int*   row = ei;       // sources
    const int*   col = ei + e;   // targets
    const float* W1 = (const float*)d_in[2];  const float* b1 = (const float*)d_in[3];
    const float* W2 = (const float*)d_in[4];  const float* b2 = (const float*)d_in[5];
    const float* W3 = (const float*)d_in[6];  const float* b3 = (const float*)d_in[7];
    const float* W4 = (const float*)d_in[8];  const float* b4 = (const float*)d_in[9];
    const float* W5 = (const float*)d_in[10]; const float* b5 = (const float*)d_in[11];
    float* out = (float*)d_out;

    char* base = (char*)d_ws;
    size_t off = 0;
    auto alloc = [&](size_t bytes) { char* p = base + off; off = align_up(off + bytes); return p; };
    float*  dis        = (float*)alloc((size_t)n * 4);
    int*    counts     = (int*)alloc((size_t)n * 4);
    int*    row_ptr    = (int*)alloc((size_t)(n + 1) * 4);
    int*    cursor     = (int*)alloc((size_t)n * 4);
    int*    blockSums  = (int*)alloc(1024 * 4);
    int*    src_sorted = (int*)alloc((size_t)e * 4);
    float*  nrm_sorted = (float*)alloc((size_t)e * 4);
    float*  S          = (float*)alloc((size_t)n * 4 * 4);
    ushort* A          = (ushort*)alloc((size_t)n * 128 * 2);
    ushort* B          = (ushort*)alloc((size_t)n * 128 * 2);
    float*  zbuf       = (float*)alloc((size_t)n * 4);
    ushort* Wp2        = (ushort*)alloc(128 * 128 * 2);
    ushort* Wp3        = (ushort*)alloc(128 * 64 * 2);
    ushort* Wp4        = (ushort*)alloc(64 * 64 * 2);
    (void)ws_size;

    const int gn = ceil_div(n, NB);
    const int ge = ceil_div(e, NB);
    const int nb1 = gn;  // <= 512

    // CSR build
    k_zero<<<gn, NB, 0, stream>>>(counts, n);
    k_count<<<ge, NB, 0, stream>>>(col, e, counts);
    k_dis<<<gn, NB, 0, stream>>>(counts, dis, n);
    k_scan1<<<nb1, NB, 0, stream>>>(counts, n, row_ptr, blockSums);
    k_scan2<<<1, 512, 0, stream>>>(blockSums, nb1);
    k_scan3<<<ceil_div(n + 1, NB), NB, 0, stream>>>(row_ptr, cursor, blockSums, n, e);
    k_fill<<<ge, NB, 0, stream>>>(row, col, e, cursor, src_sorted, nrm_sorted, dis);

    // weight packs (independent of CSR; cheap)
    k_pack<128, 128><<<ceil_div(128 * 128, NB), NB, 0, stream>>>(W2, Wp2);
    k_pack<128, 64><<<ceil_div(128 * 64, NB), NB, 0, stream>>>(W3, Wp3);
    k_pack<64, 64><<<ceil_div(64 * 64, NB), NB, 0, stream>>>(W4, Wp4);

    // Layer 1: A = bf16 relu((A_hat x) @ W1 + b1)
    k_agg3<<<gn, NB, 0, stream>>>(x, row_ptr, src_sorted, nrm_sorted, dis, S, n);
    k_l1<<<ceil_div(n, 2), 256, 0, stream>>>(S, W1, b1, A, n);

    // Layer 2: B = A @ W2 ; A = relu(agg(B) + b2)
    k_mmfma<128, 128><<<ceil_div(n, 64), 256, 0, stream>>>(A, Wp2, B, n);
    k_agg128<<<ceil_div(n, 4), 256, 0, stream>>>(B, b2, row_ptr, src_sorted, nrm_sorted, dis, A, n);

    // Layer 3: B = A @ W3 (128->64) ; A = relu(agg(B) + b3)
    k_mmfma<128, 64><<<ceil_div(n, 64), 256, 0, stream>>>(A, Wp3, B, n);
    k_agg64<<<ceil_div(n, 4), 256, 0, stream>>>(B, b3, row_ptr, src_sorted, nrm_sorted, dis, A, n);

    // Layer 4: B = A @ W4 (64->64) ; A = relu(agg(B) + b4)
    k_mmfma<64, 64><<<ceil_div(n, 64), 256, 0, stream>>>(A, Wp4, B, n);
    k_agg64<<<ceil_div(n, 4), 256, 0, stream>>>(B, b4, row_ptr, src_sorted, nrm_sorted, dis, A, n);

    // Layer 5: z = A @ W5 (64->1) ; out = agg(z) + b5
    k_dot5<<<gn, NB, 0, stream>>>(A, W5, zbuf, n);
    k_agg1<<<gn, NB, 0, stream>>>(zbuf, b5, row_ptr, src_sorted, nrm_sorted, dis, out, n);
}

// Round 3
// 354.006 us; speedup vs baseline: 1.9206x; 1.2501x over previous
//
#include <hip/hip_runtime.h>
#include <hip/hip_bf16.h>
#include <stdint.h>

// GCN 5-layer, N=100000, E=600000. bf16 pipeline + MLP-unrolled gathers.
//  - CSR build per launch (counts -> scan -> fill).
//  - GEMMs via mfma_f32_16x16x32_bf16, weights pre-packed (frag-contiguous).
//  - Aggregations gather bf16, accumulate fp32, edge loop unrolled x4 for MLP.
//  - Layer-4 aggregation fuses the 64->1 W5 projection (wave reduction).

#define NB 256

typedef __attribute__((ext_vector_type(8))) short bf16x8;
typedef __attribute__((ext_vector_type(4))) float f32x4;

static __host__ __device__ inline int ceil_div(int a, int b) { return (a + b - 1) / b; }

__device__ inline ushort f32_to_bf16(float x) {   // RNE
    uint32_t u = __float_as_uint(x);
    uint32_t r = (u + 0x7fffu + ((u >> 16) & 1u)) >> 16;
    return (ushort)r;
}
__device__ inline float bf16_lo(uint32_t u) { return __uint_as_float(u << 16); }
__device__ inline float bf16_hi(uint32_t u) { return __uint_as_float(u & 0xffff0000u); }
__device__ inline float bf16_to_f32(ushort h) { return __uint_as_float(((uint32_t)h) << 16); }

// ---------------- init: zero counts + pack weights (one launch) ----------------

template <int K, int F>
__device__ inline void pack_one(const float* __restrict__ W, ushort* __restrict__ Wp, int id) {
    constexpr int KS = K / 32;
    int j = id & 7;
    int lane = (id >> 3) & 63;
    int ts = id >> 9;
    int s = ts % KS;
    int t = ts / KS;
    int k = s * 32 + ((lane >> 4) << 3) + j;
    int f = t * 16 + (lane & 15);
    Wp[id] = f32_to_bf16(W[k * F + f]);
}

__global__ void k_init(int* __restrict__ counts, int n, int zero_blocks,
                       const float* __restrict__ W2, const float* __restrict__ W3,
                       const float* __restrict__ W4, ushort* __restrict__ Wp2,
                       ushort* __restrict__ Wp3, ushort* __restrict__ Wp4) {
    int b = blockIdx.x;
    if (b < zero_blocks) {
        int i = b * NB + threadIdx.x;
        if (i < n) counts[i] = 0;
    } else {
        int id = (b - zero_blocks) * NB + threadIdx.x;
        if (id < 16384) pack_one<128, 128>(W2, Wp2, id);
        else if (id < 24576) pack_one<128, 64>(W3, Wp3, id - 16384);
        else if (id < 28672) pack_one<64, 64>(W4, Wp4, id - 24576);
    }
}

// ---------------- CSR build ----------------

__global__ void k_count(const int* __restrict__ col, int e, int* __restrict__ counts) {
    int i = blockIdx.x * NB + threadIdx.x;
    if (i < e) atomicAdd(&counts[col[i]], 1);
}

// per-block inclusive scan -> exclusive partial; also computes dis = rsqrt(deg+1)
__global__ void k_scan1(const int* __restrict__ counts, int n,
                        int* __restrict__ partial, int* __restrict__ blockSums,
                        float* __restrict__ dis) {
    __shared__ int s[NB];
    int i = blockIdx.x * NB + threadIdx.x;
    int v = (i < n) ? counts[i] : 0;
    if (i < n) dis[i] = rsqrtf((float)(v + 1));
    s[threadIdx.x] = v;
    __syncthreads();
    for (int off = 1; off < NB; off <<= 1) {
        int t = (threadIdx.x >= off) ? s[threadIdx.x - off] : 0;
        __syncthreads();
        s[threadIdx.x] += t;
        __syncthreads();
    }
    if (i < n) partial[i] = s[threadIdx.x] - v;
    if (threadIdx.x == NB - 1) blockSums[blockIdx.x] = s[NB - 1];
}

__global__ void k_scan2(int* __restrict__ blockSums, int nb) {
    __shared__ int s[512];
    int v = (threadIdx.x < nb) ? blockSums[threadIdx.x] : 0;
    s[threadIdx.x] = v;
    __syncthreads();
    for (int off = 1; off < 512; off <<= 1) {
        int t = (threadIdx.x >= off) ? s[threadIdx.x - off] : 0;
        __syncthreads();
        s[threadIdx.x] += t;
        __syncthreads();
    }
    if (threadIdx.x < nb) blockSums[threadIdx.x] = s[threadIdx.x] - v;
}

__global__ void k_scan3(int* __restrict__ row_ptr, int* __restrict__ cursor,
                        const int* __restrict__ blockSums, int n, int e) {
    int i = blockIdx.x * NB + threadIdx.x;
    if (i < n) {
        int v = row_ptr[i] + blockSums[blockIdx.x];
        row_ptr[i] = v;
        cursor[i] = v;
    } else if (i == n) {
        row_ptr[n] = e;
    }
}

__global__ void k_fill(const int* __restrict__ row, const int* __restrict__ col, int e,
                       int* __restrict__ cursor, int* __restrict__ src_sorted,
                       float* __restrict__ nrm_sorted, const float* __restrict__ dis) {
    int i = blockIdx.x * NB + threadIdx.x;
    if (i < e) {
        int c = col[i], r = row[i];
        int pos = atomicAdd(&cursor[c], 1);
        src_sorted[pos] = r;
        nrm_sorted[pos] = dis[r] * dis[c];
    }
}

// ---------------- MFMA GEMM: Z = H @ W (bf16 in/out, fp32 accum) ----------------

template <int K, int F>
__global__ __launch_bounds__(256) void k_mmfma(const ushort* __restrict__ H,
                                               const ushort* __restrict__ Wp,
                                               ushort* __restrict__ Z, int n) {
    constexpr int KS = K / 32;
    constexpr int FT = F / 16;
    int wid = threadIdx.x >> 6;
    int lane = threadIdx.x & 63;
    int node0 = blockIdx.x * 64 + wid * 16;
    int m = lane & 15;
    int quad = lane >> 4;
    int arow = node0 + m;
    if (arow >= n) arow = n - 1;
    const bf16x8* aptr = (const bf16x8*)(H + (size_t)arow * K + quad * 8);
    bf16x8 a[KS];
#pragma unroll
    for (int s = 0; s < KS; ++s) a[s] = aptr[s * 4];
    const bf16x8* bp = (const bf16x8*)Wp;
#pragma unroll 2
    for (int t = 0; t < FT; ++t) {
        f32x4 acc = {0.f, 0.f, 0.f, 0.f};
#pragma unroll
        for (int s = 0; s < KS; ++s)
            acc = __builtin_amdgcn_mfma_f32_16x16x32_bf16(a[s], bp[(t * KS + s) * 64 + lane], acc, 0, 0, 0);
        int feat = t * 16 + m;
#pragma unroll
        for (int r = 0; r < 4; ++r) {
            int node = node0 + quad * 4 + r;
            if (node < n) Z[(size_t)node * F + feat] = f32_to_bf16(acc[r]);
        }
    }
}

// ---------------- aggregation (bf16 gather, fp32 accum, x4 unrolled) ----------------

// F=128: one wave per node, 2 features (one b32) per lane
__global__ __launch_bounds__(256) void k_agg128(const ushort* __restrict__ Z,
                                                const float* __restrict__ bias,
                                                const int* __restrict__ row_ptr,
                                                const int* __restrict__ src,
                                                const float* __restrict__ nrm,
                                                const float* __restrict__ dis,
                                                ushort* __restrict__ Out, int n) {
    int lane = threadIdx.x & 63;
    int i = blockIdx.x * 4 + (threadIdx.x >> 6);
    if (i >= n) return;
    const uint32_t* Zb = (const uint32_t*)Z;
    float d = dis[i], w = d * d;
    uint32_t u = Zb[(size_t)i * 64 + lane];
    float a0 = w * bf16_lo(u);
    float a1 = w * bf16_hi(u);
    int s0 = row_ptr[i], s1 = row_ptr[i + 1];
    int e = s0;
    for (; e + 4 <= s1; e += 4) {
        int j0 = src[e], j1 = src[e + 1], j2 = src[e + 2], j3 = src[e + 3];
        uint32_t v0 = Zb[(size_t)j0 * 64 + lane];
        uint32_t v1 = Zb[(size_t)j1 * 64 + lane];
        uint32_t v2 = Zb[(size_t)j2 * 64 + lane];
        uint32_t v3 = Zb[(size_t)j3 * 64 + lane];
        float n0 = nrm[e], n1 = nrm[e + 1], n2 = nrm[e + 2], n3 = nrm[e + 3];
        a0 += n0 * bf16_lo(v0) + n1 * bf16_lo(v1) + n2 * bf16_lo(v2) + n3 * bf16_lo(v3);
        a1 += n0 * bf16_hi(v0) + n1 * bf16_hi(v1) + n2 * bf16_hi(v2) + n3 * bf16_hi(v3);
    }
    for (; e < s1; ++e) {
        int j = src[e];
        float nv = nrm[e];
        uint32_t v = Zb[(size_t)j * 64 + lane];
        a0 += nv * bf16_lo(v);
        a1 += nv * bf16_hi(v);
    }
    a0 = fmaxf(a0 + bias[2 * lane], 0.f);
    a1 = fmaxf(a1 + bias[2 * lane + 1], 0.f);
    uint32_t o = ((uint32_t)f32_to_bf16(a1) << 16) | (uint32_t)f32_to_bf16(a0);
    *((uint32_t*)(Out + (size_t)i * 128) + lane) = o;
}

// F=64: one wave per node, 1 feature per lane
__global__ __launch_bounds__(256) void k_agg64(const ushort* __restrict__ Z,
                                               const float* __restrict__ bias,
                                               const int* __restrict__ row_ptr,
                                               const int* __restrict__ src,
                                               const float* __restrict__ nrm,
                                               const float* __restrict__ dis,
                                               ushort* __restrict__ Out, int n) {
    int lane = threadIdx.x & 63;
    int i = blockIdx.x * 4 + (threadIdx.x >> 6);
    if (i >= n) return;
    float d = dis[i];
    float acc = d * d * bf16_to_f32(Z[(size_t)i * 64 + lane]);
    int s0 = row_ptr[i], s1 = row_ptr[i + 1];
    int e = s0;
    for (; e + 4 <= s1; e += 4) {
        int j0 = src[e], j1 = src[e + 1], j2 = src[e + 2], j3 = src[e + 3];
        float v0 = bf16_to_f32(Z[(size_t)j0 * 64 + lane]);
        float v1 = bf16_to_f32(Z[(size_t)j1 * 64 + lane]);
        float v2 = bf16_to_f32(Z[(size_t)j2 * 64 + lane]);
        float v3 = bf16_to_f32(Z[(size_t)j3 * 64 + lane]);
        acc += nrm[e] * v0 + nrm[e + 1] * v1 + nrm[e + 2] * v2 + nrm[e + 3] * v3;
    }
    for (; e < s1; ++e) acc += nrm[e] * bf16_to_f32(Z[(size_t)src[e] * 64 + lane]);
    acc = fmaxf(acc + bias[lane], 0.f);
    Out[(size_t)i * 64 + lane] = f32_to_bf16(acc);
}

// Layer-4 aggregation fused with 64->1 projection: z[i] = relu(agg+b4) . W5
__global__ __launch_bounds__(256) void k_agg64z(const ushort* __restrict__ Z,
                                                const float* __restrict__ bias,
                                                const float* __restrict__ W5,
                                                const int* __restrict__ row_ptr,
                                                const int* __restrict__ src,
                                                const float* __restrict__ nrm,
                                                const float* __restrict__ dis,
                                                float* __restrict__ z, int n) {
    int lane = threadIdx.x & 63;
    int i = blockIdx.x * 4 + (threadIdx.x >> 6);
    if (i >= n) return;
    float d = dis[i];
    float acc = d * d * bf16_to_f32(Z[(size_t)i * 64 + lane]);
    int s0 = row_ptr[i], s1 = row_ptr[i + 1];
    int e = s0;
    for (; e + 4 <= s1; e += 4) {
        int j0 = src[e], j1 = src[e + 1], j2 = src[e + 2], j3 = src[e + 3];
        float v0 = bf16_to_f32(Z[(size_t)j0 * 64 + lane]);
        float v1 = bf16_to_f32(Z[(size_t)j1 * 64 + lane]);
        float v2 = bf16_to_f32(Z[(size_t)j2 * 64 + lane]);
        float v3 = bf16_to_f32(Z[(size_t)j3 * 64 + lane]);
        acc += nrm[e] * v0 + nrm[e + 1] * v1 + nrm[e + 2] * v2 + nrm[e + 3] * v3;
    }
    for (; e < s1; ++e) acc += nrm[e] * bf16_to_f32(Z[(size_t)src[e] * 64 + lane]);
    acc = fmaxf(acc + bias[lane], 0.f);
    float p = acc * W5[lane];
#pragma unroll
    for (int off = 32; off; off >>= 1) p += __shfl_xor(p, off, 64);
    if (lane == 0) z[i] = p;
}

// ---------------- layer 1 & layer 5 helpers ----------------

__global__ void k_agg3(const float* __restrict__ x, const int* __restrict__ row_ptr,
                       const int* __restrict__ src, const float* __restrict__ nrm,
                       const float* __restrict__ dis, float* __restrict__ S, int n) {
    int i = blockIdx.x * NB + threadIdx.x;
    if (i >= n) return;
    float d = dis[i], w = d * d;
    float a0 = w * x[3 * i], a1 = w * x[3 * i + 1], a2 = w * x[3 * i + 2];
    int s0 = row_ptr[i], s1 = row_ptr[i + 1];
    int e = s0;
    for (; e + 4 <= s1; e += 4) {
        int j0 = src[e], j1 = src[e + 1], j2 = src[e + 2], j3 = src[e + 3];
        float n0 = nrm[e], n1 = nrm[e + 1], n2 = nrm[e + 2], n3 = nrm[e + 3];
        a0 += n0 * x[3 * j0] + n1 * x[3 * j1] + n2 * x[3 * j2] + n3 * x[3 * j3];
        a1 += n0 * x[3 * j0 + 1] + n1 * x[3 * j1 + 1] + n2 * x[3 * j2 + 1] + n3 * x[3 * j3 + 1];
        a2 += n0 * x[3 * j0 + 2] + n1 * x[3 * j1 + 2] + n2 * x[3 * j2 + 2] + n3 * x[3 * j3 + 2];
    }
    for (; e < s1; ++e) {
        int j = src[e];
        float nv = nrm[e];
        a0 += nv * x[3 * j];
        a1 += nv * x[3 * j + 1];
        a2 += nv * x[3 * j + 2];
    }
    S[4 * i] = a0; S[4 * i + 1] = a1; S[4 * i + 2] = a2; S[4 * i + 3] = 0.f;
}

__global__ __launch_bounds__(256) void k_l1(const float* __restrict__ S,
                                            const float* __restrict__ W1,
                                            const float* __restrict__ b1,
                                            ushort* __restrict__ A, int n) {
    __shared__ float w[3][128];
    __shared__ float bb[128];
    if (threadIdx.x < 128) {
        w[0][threadIdx.x] = W1[threadIdx.x];
        w[1][threadIdx.x] = W1[128 + threadIdx.x];
        w[2][threadIdx.x] = W1[256 + threadIdx.x];
        bb[threadIdx.x] = b1[threadIdx.x];
    }
    __syncthreads();
    int f = threadIdx.x & 127;
    int i = blockIdx.x * 2 + (threadIdx.x >> 7);
    if (i >= n) return;
    float4 xv = *(const float4*)&S[4 * i];
    float v = xv.x * w[0][f] + xv.y * w[1][f] + xv.z * w[2][f] + bb[f];
    A[(size_t)i * 128 + f] = f32_to_bf16(fmaxf(v, 0.f));
}

// width-1 final aggregation (fp32, + b5)
__global__ void k_agg1(const float* __restrict__ z, const float* __restrict__ b5,
                       const int* __restrict__ row_ptr, const int* __restrict__ src,
                       const float* __restrict__ nrm, const float* __restrict__ dis,
                       float* __restrict__ out, int n) {
    int i = blockIdx.x * NB + threadIdx.x;
    if (i >= n) return;
    float d = dis[i];
    float acc = d * d * z[i];
    int s0 = row_ptr[i], s1 = row_ptr[i + 1];
    int e = s0;
    for (; e + 4 <= s1; e += 4) {
        int j0 = src[e], j1 = src[e + 1], j2 = src[e + 2], j3 = src[e + 3];
        acc += nrm[e] * z[j0] + nrm[e + 1] * z[j1] + nrm[e + 2] * z[j2] + nrm[e + 3] * z[j3];
    }
    for (; e < s1; ++e) acc += nrm[e] * z[src[e]];
    out[i] = acc + b5[0];
}

// ---------------- launch ----------------

static inline size_t align_up(size_t x) { return (x + 255) & ~(size_t)255; }

extern "C" void kernel_launch(void* const* d_in, const int* in_sizes, int n_in,
                              void* d_out, int out_size, void* d_ws, size_t ws_size,
                              hipStream_t stream) {
    const int n = in_sizes[0] / 3;   // 100000
    const int e = in_sizes[1] / 2;   // 600000

    const float* x   = (const float*)d_in[0];
    const int*   ei  = (const int*)d_in[1];
    const int*   row = ei;       // sources
    const int*   col = ei + e;   // targets
    const float* W1 = (const float*)d_in[2];  const float* b1 = (const float*)d_in[3];
    const float* W2 = (const float*)d_in[4];  const float* b2 = (const float*)d_in[5];
    const float* W3 = (const float*)d_in[6];  const float* b3 = (const float*)d_in[7];
    const float* W4 = (const float*)d_in[8];  const float* b4 = (const float*)d_in[9];
    const float* W5 = (const float*)d_in[10]; const float* b5 = (const float*)d_in[11];
    float* out = (float*)d_out;

    char* base = (char*)d_ws;
    size_t off = 0;
    auto alloc = [&](size_t bytes) { char* p = base + off; off = align_up(off + bytes); return p; };
    float*  dis        = (float*)alloc((size_t)n * 4);
    int*    counts     = (int*)alloc((size_t)n * 4);
    int*    row_ptr    = (int*)alloc((size_t)(n + 1) * 4);
    int*    cursor     = (int*)alloc((size_t)n * 4);
    int*    blockSums  = (int*)alloc(1024 * 4);
    int*    src_sorted = (int*)alloc((size_t)e * 4);
    float*  nrm_sorted = (float*)alloc((size_t)e * 4);
    float*  S          = (float*)alloc((size_t)n * 4 * 4);
    ushort* A          = (ushort*)alloc((size_t)n * 128 * 2);
    ushort* B          = (ushort*)alloc((size_t)n * 128 * 2);
    float*  zbuf       = (float*)alloc((size_t)n * 4);
    ushort* Wp2        = (ushort*)alloc(128 * 128 * 2);
    ushort* Wp3        = (ushort*)alloc(128 * 64 * 2);
    ushort* Wp4        = (ushort*)alloc(64 * 64 * 2);
    (void)ws_size;

    const int gn = ceil_div(n, NB);        // 391
    const int ge = ceil_div(e, NB);        // 2344
    const int nb1 = gn;                    // <= 512 for scan2
    const int pack_blocks = ceil_div(16384 + 8192 + 4096, NB);  // 112

    // init (zero counts + pack all weights) + CSR build
    k_init<<<gn + pack_blocks, NB, 0, stream>>>(counts, n, gn, W2, W3, W4, Wp2, Wp3, Wp4);
    k_count<<<ge, NB, 0, stream>>>(col, e, counts);
    k_scan1<<<nb1, NB, 0, stream>>>(counts, n, row_ptr, blockSums, dis);
    k_scan2<<<1, 512, 0, stream>>>(blockSums, nb1);
    k_scan3<<<ceil_div(n + 1, NB), NB, 0, stream>>>(row_ptr, cursor, blockSums, n, e);
    k_fill<<<ge, NB, 0, stream>>>(row, col, e, cursor, src_sorted, nrm_sorted, dis);

    // Layer 1: A = bf16 relu((A_hat x) @ W1 + b1)
    k_agg3<<<gn, NB, 0, stream>>>(x, row_ptr, src_sorted, nrm_sorted, dis, S, n);
    k_l1<<<ceil_div(n, 2), 256, 0, stream>>>(S, W1, b1, A, n);

    // Layer 2
    k_mmfma<128, 128><<<ceil_div(n, 64), 256, 0, stream>>>(A, Wp2, B, n);
    k_agg128<<<ceil_div(n, 4), 256, 0, stream>>>(B, b2, row_ptr, src_sorted, nrm_sorted, dis, A, n);

    // Layer 3
    k_mmfma<128, 64><<<ceil_div(n, 64), 256, 0, stream>>>(A, Wp3, B, n);
    k_agg64<<<ceil_div(n, 4), 256, 0, stream>>>(B, b3, row_ptr, src_sorted, nrm_sorted, dis, A, n);

    // Layer 4 (+ fused W5 projection)
    k_mmfma<64, 64><<<ceil_div(n, 64), 256, 0, stream>>>(A, Wp4, B, n);
    k_agg64z<<<ceil_div(n, 4), 256, 0, stream>>>(B, b4, W5, row_ptr, src_sorted, nrm_sorted, dis, zbuf, n);

    // Layer 5: out = A_hat z + b5
    k_agg1<<<gn, NB, 0, stream>>>(zbuf, b5, row_ptr, src_sorted, nrm_sorted, dis, out, n);
}

// Round 4
// 303.468 us; speedup vs baseline: 2.2405x; 1.1665x over previous
//
#include <hip/hip_runtime.h>
#include <hip/hip_bf16.h>
#include <stdint.h>

// GCN 5-layer, N=100000, E=600000. bf16 pipeline, AoS edge records,
// sub-wave aggregation (half-wave per node @F=128, quarter-wave @F=64).
//  - CSR build per launch; edge record = uint2{src, nrm_bits} (one 8B store).
//  - GEMMs via mfma_f32_16x16x32_bf16, weights pre-packed frag-contiguous.
//  - Aggregations gather bf16 rows, fp32 accum, x4 edge unroll.
//  - Layer-4 agg fuses the 64->1 W5 projection (quarter-wave reduction).

#define NB 256

typedef __attribute__((ext_vector_type(8))) short bf16x8;
typedef __attribute__((ext_vector_type(4))) float f32x4;

static __host__ __device__ inline int ceil_div(int a, int b) { return (a + b - 1) / b; }

__device__ inline ushort f32_to_bf16(float x) {   // RNE
    uint32_t u = __float_as_uint(x);
    uint32_t r = (u + 0x7fffu + ((u >> 16) & 1u)) >> 16;
    return (ushort)r;
}
__device__ inline float bf16_lo(uint32_t u) { return __uint_as_float(u << 16); }
__device__ inline float bf16_hi(uint32_t u) { return __uint_as_float(u & 0xffff0000u); }
__device__ inline float bf16_to_f32(ushort h) { return __uint_as_float(((uint32_t)h) << 16); }

// ---------------- init: zero counts + pack weights (one launch) ----------------

template <int K, int F>
__device__ inline void pack_one(const float* __restrict__ W, ushort* __restrict__ Wp, int id) {
    constexpr int KS = K / 32;
    int j = id & 7;
    int lane = (id >> 3) & 63;
    int ts = id >> 9;
    int s = ts % KS;
    int t = ts / KS;
    int k = s * 32 + ((lane >> 4) << 3) + j;
    int f = t * 16 + (lane & 15);
    Wp[id] = f32_to_bf16(W[k * F + f]);
}

__global__ void k_init(int* __restrict__ counts, int n, int zero_blocks,
                       const float* __restrict__ W2, const float* __restrict__ W3,
                       const float* __restrict__ W4, ushort* __restrict__ Wp2,
                       ushort* __restrict__ Wp3, ushort* __restrict__ Wp4) {
    int b = blockIdx.x;
    if (b < zero_blocks) {
        int i = b * NB + threadIdx.x;
        if (i < n) counts[i] = 0;
    } else {
        int id = (b - zero_blocks) * NB + threadIdx.x;
        if (id < 16384) pack_one<128, 128>(W2, Wp2, id);
        else if (id < 24576) pack_one<128, 64>(W3, Wp3, id - 16384);
        else if (id < 28672) pack_one<64, 64>(W4, Wp4, id - 24576);
    }
}

// ---------------- CSR build ----------------

__global__ void k_count(const int* __restrict__ col, int e, int* __restrict__ counts) {
    int i = blockIdx.x * NB + threadIdx.x;
    if (i < e) atomicAdd(&counts[col[i]], 1);
}

__global__ void k_scan1(const int* __restrict__ counts, int n,
                        int* __restrict__ partial, int* __restrict__ blockSums,
                        float* __restrict__ dis) {
    __shared__ int s[NB];
    int i = blockIdx.x * NB + threadIdx.x;
    int v = (i < n) ? counts[i] : 0;
    if (i < n) dis[i] = rsqrtf((float)(v + 1));
    s[threadIdx.x] = v;
    __syncthreads();
    for (int off = 1; off < NB; off <<= 1) {
        int t = (threadIdx.x >= off) ? s[threadIdx.x - off] : 0;
        __syncthreads();
        s[threadIdx.x] += t;
        __syncthreads();
    }
    if (i < n) partial[i] = s[threadIdx.x] - v;
    if (threadIdx.x == NB - 1) blockSums[blockIdx.x] = s[NB - 1];
}

__global__ void k_scan2(int* __restrict__ blockSums, int nb) {
    __shared__ int s[512];
    int v = (threadIdx.x < nb) ? blockSums[threadIdx.x] : 0;
    s[threadIdx.x] = v;
    __syncthreads();
    for (int off = 1; off < 512; off <<= 1) {
        int t = (threadIdx.x >= off) ? s[threadIdx.x - off] : 0;
        __syncthreads();
        s[threadIdx.x] += t;
        __syncthreads();
    }
    if (threadIdx.x < nb) blockSums[threadIdx.x] = s[threadIdx.x] - v;
}

__global__ void k_scan3(int* __restrict__ row_ptr, int* __restrict__ cursor,
                        const int* __restrict__ blockSums, int n, int e) {
    int i = blockIdx.x * NB + threadIdx.x;
    if (i < n) {
        int v = row_ptr[i] + blockSums[blockIdx.x];
        row_ptr[i] = v;
        cursor[i] = v;
    } else if (i == n) {
        row_ptr[n] = e;
    }
}

// edge record: uint2 {src, nrm_bits} — single 8B scatter store
__global__ void k_fill(const int* __restrict__ row, const int* __restrict__ col, int e,
                       int* __restrict__ cursor, uint2* __restrict__ edges,
                       const float* __restrict__ dis) {
    int i = blockIdx.x * NB + threadIdx.x;
    if (i < e) {
        int c = col[i], r = row[i];
        int pos = atomicAdd(&cursor[c], 1);
        edges[pos] = make_uint2((uint32_t)r, __float_as_uint(dis[r] * dis[c]));
    }
}

// ---------------- MFMA GEMM: Z = H @ W (bf16 in/out, fp32 accum) ----------------

template <int K, int F>
__global__ __launch_bounds__(256) void k_mmfma(const ushort* __restrict__ H,
                                               const ushort* __restrict__ Wp,
                                               ushort* __restrict__ Z, int n) {
    constexpr int KS = K / 32;
    constexpr int FT = F / 16;
    int wid = threadIdx.x >> 6;
    int lane = threadIdx.x & 63;
    int node0 = blockIdx.x * 64 + wid * 16;
    int m = lane & 15;
    int quad = lane >> 4;
    int arow = node0 + m;
    if (arow >= n) arow = n - 1;
    const bf16x8* aptr = (const bf16x8*)(H + (size_t)arow * K + quad * 8);
    bf16x8 a[KS];
#pragma unroll
    for (int s = 0; s < KS; ++s) a[s] = aptr[s * 4];
    const bf16x8* bp = (const bf16x8*)Wp;
#pragma unroll 2
    for (int t = 0; t < FT; ++t) {
        f32x4 acc = {0.f, 0.f, 0.f, 0.f};
#pragma unroll
        for (int s = 0; s < KS; ++s)
            acc = __builtin_amdgcn_mfma_f32_16x16x32_bf16(a[s], bp[(t * KS + s) * 64 + lane], acc, 0, 0, 0);
        int feat = t * 16 + m;
#pragma unroll
        for (int r = 0; r < 4; ++r) {
            int node = node0 + quad * 4 + r;
            if (node < n) Z[(size_t)node * F + feat] = f32_to_bf16(acc[r]);
        }
    }
}

// ---------------- aggregation (bf16 gather, fp32 accum) ----------------
// 4 features per lane via uint2; sub-wave per node for edge-stream MLP.

__device__ inline void fma4(float (&a)[4], float nv, uint2 v) {
    a[0] += nv * bf16_lo(v.x);
    a[1] += nv * bf16_hi(v.x);
    a[2] += nv * bf16_lo(v.y);
    a[3] += nv * bf16_hi(v.y);
}

// F=128: half-wave (32 lanes) per node, 8 nodes per 256-block
__global__ __launch_bounds__(256) void k_agg128(const ushort* __restrict__ Z,
                                                const float* __restrict__ bias,
                                                const int* __restrict__ row_ptr,
                                                const uint2* __restrict__ edges,
                                                const float* __restrict__ dis,
                                                ushort* __restrict__ Out, int n) {
    int l = threadIdx.x & 31;
    int i = blockIdx.x * 8 + (threadIdx.x >> 5);
    if (i >= n) return;
    const uint2* Zr = (const uint2*)Z;   // 32 uint2 per row
    float d = dis[i], w = d * d;
    float a[4] = {0.f, 0.f, 0.f, 0.f};
    fma4(a, w, Zr[(size_t)i * 32 + l]);
    int s0 = row_ptr[i], s1 = row_ptr[i + 1];
    int e = s0;
    for (; e + 4 <= s1; e += 4) {
        uint2 e0 = edges[e], e1 = edges[e + 1], e2 = edges[e + 2], e3 = edges[e + 3];
        uint2 v0 = Zr[(size_t)e0.x * 32 + l];
        uint2 v1 = Zr[(size_t)e1.x * 32 + l];
        uint2 v2 = Zr[(size_t)e2.x * 32 + l];
        uint2 v3 = Zr[(size_t)e3.x * 32 + l];
        fma4(a, __uint_as_float(e0.y), v0);
        fma4(a, __uint_as_float(e1.y), v1);
        fma4(a, __uint_as_float(e2.y), v2);
        fma4(a, __uint_as_float(e3.y), v3);
    }
    for (; e < s1; ++e) {
        uint2 er = edges[e];
        fma4(a, __uint_as_float(er.y), Zr[(size_t)er.x * 32 + l]);
    }
    float4 bb = *(const float4*)&bias[4 * l];
    a[0] = fmaxf(a[0] + bb.x, 0.f);
    a[1] = fmaxf(a[1] + bb.y, 0.f);
    a[2] = fmaxf(a[2] + bb.z, 0.f);
    a[3] = fmaxf(a[3] + bb.w, 0.f);
    uint2 o;
    o.x = ((uint32_t)f32_to_bf16(a[1]) << 16) | (uint32_t)f32_to_bf16(a[0]);
    o.y = ((uint32_t)f32_to_bf16(a[3]) << 16) | (uint32_t)f32_to_bf16(a[2]);
    ((uint2*)Out)[(size_t)i * 32 + l] = o;
}

// F=64: quarter-wave (16 lanes) per node, 16 nodes per 256-block
__global__ __launch_bounds__(256) void k_agg64(const ushort* __restrict__ Z,
                                               const float* __restrict__ bias,
                                               const int* __restrict__ row_ptr,
                                               const uint2* __restrict__ edges,
                                               const float* __restrict__ dis,
                                               ushort* __restrict__ Out, int n) {
    int l = threadIdx.x & 15;
    int i = blockIdx.x * 16 + (threadIdx.x >> 4);
    if (i >= n) return;
    const uint2* Zr = (const uint2*)Z;   // 16 uint2 per row
    float d = dis[i], w = d * d;
    float a[4] = {0.f, 0.f, 0.f, 0.f};
    fma4(a, w, Zr[(size_t)i * 16 + l]);
    int s0 = row_ptr[i], s1 = row_ptr[i + 1];
    int e = s0;
    for (; e + 4 <= s1; e += 4) {
        uint2 e0 = edges[e], e1 = edges[e + 1], e2 = edges[e + 2], e3 = edges[e + 3];
        uint2 v0 = Zr[(size_t)e0.x * 16 + l];
        uint2 v1 = Zr[(size_t)e1.x * 16 + l];
        uint2 v2 = Zr[(size_t)e2.x * 16 + l];
        uint2 v3 = Zr[(size_t)e3.x * 16 + l];
        fma4(a, __uint_as_float(e0.y), v0);
        fma4(a, __uint_as_float(e1.y), v1);
        fma4(a, __uint_as_float(e2.y), v2);
        fma4(a, __uint_as_float(e3.y), v3);
    }
    for (; e < s1; ++e) {
        uint2 er = edges[e];
        fma4(a, __uint_as_float(er.y), Zr[(size_t)er.x * 16 + l]);
    }
    float4 bb = *(const float4*)&bias[4 * l];
    a[0] = fmaxf(a[0] + bb.x, 0.f);
    a[1] = fmaxf(a[1] + bb.y, 0.f);
    a[2] = fmaxf(a[2] + bb.z, 0.f);
    a[3] = fmaxf(a[3] + bb.w, 0.f);
    uint2 o;
    o.x = ((uint32_t)f32_to_bf16(a[1]) << 16) | (uint32_t)f32_to_bf16(a[0]);
    o.y = ((uint32_t)f32_to_bf16(a[3]) << 16) | (uint32_t)f32_to_bf16(a[2]);
    ((uint2*)Out)[(size_t)i * 16 + l] = o;
}

// Layer-4 agg (F=64) fused with 64->1 W5 projection: z[i] = relu(agg+b4) . W5
__global__ __launch_bounds__(256) void k_agg64z(const ushort* __restrict__ Z,
                                                const float* __restrict__ bias,
                                                const float* __restrict__ W5,
                                                const int* __restrict__ row_ptr,
                                                const uint2* __restrict__ edges,
                                                const float* __restrict__ dis,
                                                float* __restrict__ z, int n) {
    int l = threadIdx.x & 15;
    int i = blockIdx.x * 16 + (threadIdx.x >> 4);
    if (i >= n) return;
    const uint2* Zr = (const uint2*)Z;
    float d = dis[i], w = d * d;
    float a[4] = {0.f, 0.f, 0.f, 0.f};
    fma4(a, w, Zr[(size_t)i * 16 + l]);
    int s0 = row_ptr[i], s1 = row_ptr[i + 1];
    int e = s0;
    for (; e + 4 <= s1; e += 4) {
        uint2 e0 = edges[e], e1 = edges[e + 1], e2 = edges[e + 2], e3 = edges[e + 3];
        uint2 v0 = Zr[(size_t)e0.x * 16 + l];
        uint2 v1 = Zr[(size_t)e1.x * 16 + l];
        uint2 v2 = Zr[(size_t)e2.x * 16 + l];
        uint2 v3 = Zr[(size_t)e3.x * 16 + l];
        fma4(a, __uint_as_float(e0.y), v0);
        fma4(a, __uint_as_float(e1.y), v1);
        fma4(a, __uint_as_float(e2.y), v2);
        fma4(a, __uint_as_float(e3.y), v3);
    }
    for (; e < s1; ++e) {
        uint2 er = edges[e];
        fma4(a, __uint_as_float(er.y), Zr[(size_t)er.x * 16 + l]);
    }
    float4 bb = *(const float4*)&bias[4 * l];
    float4 wv = *(const float4*)&W5[4 * l];
    float p = fmaxf(a[0] + bb.x, 0.f) * wv.x + fmaxf(a[1] + bb.y, 0.f) * wv.y +
              fmaxf(a[2] + bb.z, 0.f) * wv.z + fmaxf(a[3] + bb.w, 0.f) * wv.w;
#pragma unroll
    for (int off = 8; off; off >>= 1) p += __shfl_xor(p, off, 64);
    if (l == 0) z[i] = p;
}

// ---------------- layer 1 & layer 5 helpers ----------------

__global__ void k_agg3(const float* __restrict__ x, const int* __restrict__ row_ptr,
                       const uint2* __restrict__ edges, const float* __restrict__ dis,
                       float* __restrict__ S, int n) {
    int i = blockIdx.x * NB + threadIdx.x;
    if (i >= n) return;
    float d = dis[i], w = d * d;
    float a0 = w * x[3 * i], a1 = w * x[3 * i + 1], a2 = w * x[3 * i + 2];
    int s0 = row_ptr[i], s1 = row_ptr[i + 1];
    int e = s0;
    for (; e + 4 <= s1; e += 4) {
        uint2 e0 = edges[e], e1 = edges[e + 1], e2 = edges[e + 2], e3 = edges[e + 3];
        int j0 = e0.x, j1 = e1.x, j2 = e2.x, j3 = e3.x;
        float n0 = __uint_as_float(e0.y), n1 = __uint_as_float(e1.y);
        float n2 = __uint_as_float(e2.y), n3 = __uint_as_float(e3.y);
        a0 += n0 * x[3 * j0] + n1 * x[3 * j1] + n2 * x[3 * j2] + n3 * x[3 * j3];
        a1 += n0 * x[3 * j0 + 1] + n1 * x[3 * j1 + 1] + n2 * x[3 * j2 + 1] + n3 * x[3 * j3 + 1];
        a2 += n0 * x[3 * j0 + 2] + n1 * x[3 * j1 + 2] + n2 * x[3 * j2 + 2] + n3 * x[3 * j3 + 2];
    }
    for (; e < s1; ++e) {
        uint2 er = edges[e];
        int j = er.x;
        float nv = __uint_as_float(er.y);
        a0 += nv * x[3 * j];
        a1 += nv * x[3 * j + 1];
        a2 += nv * x[3 * j + 2];
    }
    S[4 * i] = a0; S[4 * i + 1] = a1; S[4 * i + 2] = a2; S[4 * i + 3] = 0.f;
}

__global__ __launch_bounds__(256) void k_l1(const float* __restrict__ S,
                                            const float* __restrict__ W1,
                                            const float* __restrict__ b1,
                                            ushort* __restrict__ A, int n) {
    __shared__ float w[3][128];
    __shared__ float bb[128];
    if (threadIdx.x < 128) {
        w[0][threadIdx.x] = W1[threadIdx.x];
        w[1][threadIdx.x] = W1[128 + threadIdx.x];
        w[2][threadIdx.x] = W1[256 + threadIdx.x];
        bb[threadIdx.x] = b1[threadIdx.x];
    }
    __syncthreads();
    int f = threadIdx.x & 127;
    int i = blockIdx.x * 2 + (threadIdx.x >> 7);
    if (i >= n) return;
    float4 xv = *(const float4*)&S[4 * i];
    float v = xv.x * w[0][f] + xv.y * w[1][f] + xv.z * w[2][f] + bb[f];
    A[(size_t)i * 128 + f] = f32_to_bf16(fmaxf(v, 0.f));
}

// width-1 final aggregation (fp32, + b5)
__global__ void k_agg1(const float* __restrict__ z, const float* __restrict__ b5,
                       const int* __restrict__ row_ptr, const uint2* __restrict__ edges,
                       const float* __restrict__ dis, float* __restrict__ out, int n) {
    int i = blockIdx.x * NB + threadIdx.x;
    if (i >= n) return;
    float d = dis[i];
    float acc = d * d * z[i];
    int s0 = row_ptr[i], s1 = row_ptr[i + 1];
    int e = s0;
    for (; e + 4 <= s1; e += 4) {
        uint2 e0 = edges[e], e1 = edges[e + 1], e2 = edges[e + 2], e3 = edges[e + 3];
        acc += __uint_as_float(e0.y) * z[e0.x] + __uint_as_float(e1.y) * z[e1.x] +
               __uint_as_float(e2.y) * z[e2.x] + __uint_as_float(e3.y) * z[e3.x];
    }
    for (; e < s1; ++e) {
        uint2 er = edges[e];
        acc += __uint_as_float(er.y) * z[er.x];
    }
    out[i] = acc + b5[0];
}

// ---------------- launch ----------------

static inline size_t align_up(size_t x) { return (x + 255) & ~(size_t)255; }

extern "C" void kernel_launch(void* const* d_in, const int* in_sizes, int n_in,
                              void* d_out, int out_size, void* d_ws, size_t ws_size,
                              hipStream_t stream) {
    const int n = in_sizes[0] / 3;   // 100000
    const int e = in_sizes[1] / 2;   // 600000

    const float* x   = (const float*)d_in[0];
    const int*   ei  = (const int*)d_in[1];
    const int*   row = ei;       // sources
    const int*   col = ei + e;   // targets
    const float* W1 = (const float*)d_in[2];  const float* b1 = (const float*)d_in[3];
    const float* W2 = (const float*)d_in[4];  const float* b2 = (const float*)d_in[5];
    const float* W3 = (const float*)d_in[6];  const float* b3 = (const float*)d_in[7];
    const float* W4 = (const float*)d_in[8];  const float* b4 = (const float*)d_in[9];
    const float* W5 = (const float*)d_in[10]; const float* b5 = (const float*)d_in[11];
    float* out = (float*)d_out;

    char* base = (char*)d_ws;
    size_t off = 0;
    auto alloc = [&](size_t bytes) { char* p = base + off; off = align_up(off + bytes); return p; };
    float*  dis        = (float*)alloc((size_t)n * 4);
    int*    counts     = (int*)alloc((size_t)n * 4);
    int*    row_ptr    = (int*)alloc((size_t)(n + 1) * 4);
    int*    cursor     = (int*)alloc((size_t)n * 4);
    int*    blockSums  = (int*)alloc(1024 * 4);
    uint2*  edges      = (uint2*)alloc((size_t)e * 8);
    float*  S          = (float*)alloc((size_t)n * 4 * 4);
    ushort* A          = (ushort*)alloc((size_t)n * 128 * 2);
    ushort* B          = (ushort*)alloc((size_t)n * 128 * 2);
    float*  zbuf       = (float*)alloc((size_t)n * 4);
    ushort* Wp2        = (ushort*)alloc(128 * 128 * 2);
    ushort* Wp3        = (ushort*)alloc(128 * 64 * 2);
    ushort* Wp4        = (ushort*)alloc(64 * 64 * 2);
    (void)ws_size;

    const int gn = ceil_div(n, NB);        // 391
    const int ge = ceil_div(e, NB);        // 2344
    const int nb1 = gn;                    // <= 512 for scan2
    const int pack_blocks = ceil_div(16384 + 8192 + 4096, NB);  // 112

    // init (zero counts + pack weights) + CSR build
    k_init<<<gn + pack_blocks, NB, 0, stream>>>(counts, n, gn, W2, W3, W4, Wp2, Wp3, Wp4);
    k_count<<<ge, NB, 0, stream>>>(col, e, counts);
    k_scan1<<<nb1, NB, 0, stream>>>(counts, n, row_ptr, blockSums, dis);
    k_scan2<<<1, 512, 0, stream>>>(blockSums, nb1);
    k_scan3<<<ceil_div(n + 1, NB), NB, 0, stream>>>(row_ptr, cursor, blockSums, n, e);
    k_fill<<<ge, NB, 0, stream>>>(row, col, e, cursor, edges, dis);

    // Layer 1: A = bf16 relu((A_hat x) @ W1 + b1)
    k_agg3<<<gn, NB, 0, stream>>>(x, row_ptr, edges, dis, S, n);
    k_l1<<<ceil_div(n, 2), 256, 0, stream>>>(S, W1, b1, A, n);

    // Layer 2
    k_mmfma<128, 128><<<ceil_div(n, 64), 256, 0, stream>>>(A, Wp2, B, n);
    k_agg128<<<ceil_div(n, 8), 256, 0, stream>>>(B, b2, row_ptr, edges, dis, A, n);

    // Layer 3
    k_mmfma<128, 64><<<ceil_div(n, 64), 256, 0, stream>>>(A, Wp3, B, n);
    k_agg64<<<ceil_div(n, 16), 256, 0, stream>>>(B, b3, row_ptr, edges, dis, A, n);

    // Layer 4 (+ fused W5 projection)
    k_mmfma<64, 64><<<ceil_div(n, 64), 256, 0, stream>>>(A, Wp4, B, n);
    k_agg64z<<<ceil_div(n, 16), 256, 0, stream>>>(B, b4, W5, row_ptr, edges, dis, zbuf, n);

    // Layer 5: out = A_hat z + b5
    k_agg1<<<gn, NB, 0, stream>>>(zbuf, b5, row_ptr, edges, dis, out, n);
}

// Round 5
// 273.233 us; speedup vs baseline: 2.4884x; 1.1107x over previous
//
#include <hip/hip_runtime.h>
#include <hip/hip_bf16.h>
#include <stdint.h>

// GCN 5-layer, N=100000, E=600000. bf16 pipeline, AoS edge records,
// sub-wave aggregation: 16 lanes x uint4 per node @F=128, 8 lanes @F=64.
//  - CSR build per launch; edge record = uint2{src, nrm_bits}.
//  - GEMMs via mfma_f32_16x16x32_bf16, weights pre-packed frag-contiguous.
//  - Layer 1 fused: per-thread 3-wide aggregate -> 3x128 expand (W1 in LDS).
//  - Layer-4 agg fuses the 64->1 W5 projection (8-lane reduction).

#define NB 256

typedef __attribute__((ext_vector_type(8))) short bf16x8;
typedef __attribute__((ext_vector_type(4))) float f32x4;

static __host__ __device__ inline int ceil_div(int a, int b) { return (a + b - 1) / b; }

__device__ inline ushort f32_to_bf16(float x) {   // RNE
    uint32_t u = __float_as_uint(x);
    uint32_t r = (u + 0x7fffu + ((u >> 16) & 1u)) >> 16;
    return (ushort)r;
}
__device__ inline float bf16_lo(uint32_t u) { return __uint_as_float(u << 16); }
__device__ inline float bf16_hi(uint32_t u) { return __uint_as_float(u & 0xffff0000u); }

// ---------------- init: zero counts + pack weights (one launch) ----------------

template <int K, int F>
__device__ inline void pack_one(const float* __restrict__ W, ushort* __restrict__ Wp, int id) {
    constexpr int KS = K / 32;
    int j = id & 7;
    int lane = (id >> 3) & 63;
    int ts = id >> 9;
    int s = ts % KS;
    int t = ts / KS;
    int k = s * 32 + ((lane >> 4) << 3) + j;
    int f = t * 16 + (lane & 15);
    Wp[id] = f32_to_bf16(W[k * F + f]);
}

__global__ void k_init(int* __restrict__ counts, int n, int zero_blocks,
                       const float* __restrict__ W2, const float* __restrict__ W3,
                       const float* __restrict__ W4, ushort* __restrict__ Wp2,
                       ushort* __restrict__ Wp3, ushort* __restrict__ Wp4) {
    int b = blockIdx.x;
    if (b < zero_blocks) {
        int i = b * NB + threadIdx.x;
        if (i < n) counts[i] = 0;
    } else {
        int id = (b - zero_blocks) * NB + threadIdx.x;
        if (id < 16384) pack_one<128, 128>(W2, Wp2, id);
        else if (id < 24576) pack_one<128, 64>(W3, Wp3, id - 16384);
        else if (id < 28672) pack_one<64, 64>(W4, Wp4, id - 24576);
    }
}

// ---------------- CSR build ----------------

__global__ void k_count(const int* __restrict__ col, int e, int* __restrict__ counts) {
    int i = blockIdx.x * NB + threadIdx.x;
    if (i < e) atomicAdd(&counts[col[i]], 1);
}

__global__ void k_scan1(const int* __restrict__ counts, int n,
                        int* __restrict__ partial, int* __restrict__ blockSums,
                        float* __restrict__ dis) {
    __shared__ int s[NB];
    int i = blockIdx.x * NB + threadIdx.x;
    int v = (i < n) ? counts[i] : 0;
    if (i < n) dis[i] = rsqrtf((float)(v + 1));
    s[threadIdx.x] = v;
    __syncthreads();
    for (int off = 1; off < NB; off <<= 1) {
        int t = (threadIdx.x >= off) ? s[threadIdx.x - off] : 0;
        __syncthreads();
        s[threadIdx.x] += t;
        __syncthreads();
    }
    if (i < n) partial[i] = s[threadIdx.x] - v;
    if (threadIdx.x == NB - 1) blockSums[blockIdx.x] = s[NB - 1];
}

__global__ void k_scan2(int* __restrict__ blockSums, int nb) {
    __shared__ int s[512];
    int v = (threadIdx.x < nb) ? blockSums[threadIdx.x] : 0;
    s[threadIdx.x] = v;
    __syncthreads();
    for (int off = 1; off < 512; off <<= 1) {
        int t = (threadIdx.x >= off) ? s[threadIdx.x - off] : 0;
        __syncthreads();
        s[threadIdx.x] += t;
        __syncthreads();
    }
    if (threadIdx.x < nb) blockSums[threadIdx.x] = s[threadIdx.x] - v;
}

__global__ void k_scan3(int* __restrict__ row_ptr, int* __restrict__ cursor,
                        const int* __restrict__ blockSums, int n, int e) {
    int i = blockIdx.x * NB + threadIdx.x;
    if (i < n) {
        int v = row_ptr[i] + blockSums[blockIdx.x];
        row_ptr[i] = v;
        cursor[i] = v;
    } else if (i == n) {
        row_ptr[n] = e;
    }
}

__global__ void k_fill(const int* __restrict__ row, const int* __restrict__ col, int e,
                       int* __restrict__ cursor, uint2* __restrict__ edges,
                       const float* __restrict__ dis) {
    int i = blockIdx.x * NB + threadIdx.x;
    if (i < e) {
        int c = col[i], r = row[i];
        int pos = atomicAdd(&cursor[c], 1);
        edges[pos] = make_uint2((uint32_t)r, __float_as_uint(dis[r] * dis[c]));
    }
}

// ---------------- MFMA GEMM: Z = H @ W (bf16 in/out, fp32 accum) ----------------

template <int K, int F>
__global__ __launch_bounds__(256) void k_mmfma(const ushort* __restrict__ H,
                                               const ushort* __restrict__ Wp,
                                               ushort* __restrict__ Z, int n) {
    constexpr int KS = K / 32;
    constexpr int FT = F / 16;
    int wid = threadIdx.x >> 6;
    int lane = threadIdx.x & 63;
    int node0 = blockIdx.x * 64 + wid * 16;
    int m = lane & 15;
    int quad = lane >> 4;
    int arow = node0 + m;
    if (arow >= n) arow = n - 1;
    const bf16x8* aptr = (const bf16x8*)(H + (size_t)arow * K + quad * 8);
    bf16x8 a[KS];
#pragma unroll
    for (int s = 0; s < KS; ++s) a[s] = aptr[s * 4];
    const bf16x8* bp = (const bf16x8*)Wp;
#pragma unroll 2
    for (int t = 0; t < FT; ++t) {
        f32x4 acc = {0.f, 0.f, 0.f, 0.f};
#pragma unroll
        for (int s = 0; s < KS; ++s)
            acc = __builtin_amdgcn_mfma_f32_16x16x32_bf16(a[s], bp[(t * KS + s) * 64 + lane], acc, 0, 0, 0);
        int feat = t * 16 + m;
#pragma unroll
        for (int r = 0; r < 4; ++r) {
            int node = node0 + quad * 4 + r;
            if (node < n) Z[(size_t)node * F + feat] = f32_to_bf16(acc[r]);
        }
    }
}

// ---------------- aggregation (bf16 gather, fp32 accum) ----------------
// 8 features per lane via uint4; sub-wave per node for edge-stream MLP.

__device__ inline void fma8(float (&a)[8], float nv, uint4 v) {
    a[0] += nv * bf16_lo(v.x);
    a[1] += nv * bf16_hi(v.x);
    a[2] += nv * bf16_lo(v.y);
    a[3] += nv * bf16_hi(v.y);
    a[4] += nv * bf16_lo(v.z);
    a[5] += nv * bf16_hi(v.z);
    a[6] += nv * bf16_lo(v.w);
    a[7] += nv * bf16_hi(v.w);
}

// generic sub-wave agg body: L lanes per node, row = L uint4
template <int L>
__device__ inline void agg_body(float (&a)[8], const uint4* __restrict__ Zq,
                                const uint2* __restrict__ edges, int l, int i,
                                float w, int s0, int s1) {
    fma8(a, w, Zq[(size_t)i * L + l]);
    int e = s0;
    for (; e + 4 <= s1; e += 4) {
        uint2 e0 = edges[e], e1 = edges[e + 1], e2 = edges[e + 2], e3 = edges[e + 3];
        uint4 v0 = Zq[(size_t)e0.x * L + l];
        uint4 v1 = Zq[(size_t)e1.x * L + l];
        uint4 v2 = Zq[(size_t)e2.x * L + l];
        uint4 v3 = Zq[(size_t)e3.x * L + l];
        fma8(a, __uint_as_float(e0.y), v0);
        fma8(a, __uint_as_float(e1.y), v1);
        fma8(a, __uint_as_float(e2.y), v2);
        fma8(a, __uint_as_float(e3.y), v3);
    }
    for (; e < s1; ++e) {
        uint2 er = edges[e];
        fma8(a, __uint_as_float(er.y), Zq[(size_t)er.x * L + l]);
    }
}

__device__ inline uint4 pack8(const float (&a)[8], const float* __restrict__ bias, int l) {
    float4 b0 = *(const float4*)&bias[8 * l];
    float4 b1 = *(const float4*)&bias[8 * l + 4];
    float r0 = fmaxf(a[0] + b0.x, 0.f), r1 = fmaxf(a[1] + b0.y, 0.f);
    float r2 = fmaxf(a[2] + b0.z, 0.f), r3 = fmaxf(a[3] + b0.w, 0.f);
    float r4 = fmaxf(a[4] + b1.x, 0.f), r5 = fmaxf(a[5] + b1.y, 0.f);
    float r6 = fmaxf(a[6] + b1.z, 0.f), r7 = fmaxf(a[7] + b1.w, 0.f);
    uint4 o;
    o.x = ((uint32_t)f32_to_bf16(r1) << 16) | (uint32_t)f32_to_bf16(r0);
    o.y = ((uint32_t)f32_to_bf16(r3) << 16) | (uint32_t)f32_to_bf16(r2);
    o.z = ((uint32_t)f32_to_bf16(r5) << 16) | (uint32_t)f32_to_bf16(r4);
    o.w = ((uint32_t)f32_to_bf16(r7) << 16) | (uint32_t)f32_to_bf16(r6);
    return o;
}

// F=128: 16 lanes per node, 16 nodes per 256-block
__global__ __launch_bounds__(256) void k_agg128(const ushort* __restrict__ Z,
                                                const float* __restrict__ bias,
                                                const int* __restrict__ row_ptr,
                                                const uint2* __restrict__ edges,
                                                const float* __restrict__ dis,
                                                ushort* __restrict__ Out, int n) {
    int l = threadIdx.x & 15;
    int i = blockIdx.x * 16 + (threadIdx.x >> 4);
    if (i >= n) return;
    float d = dis[i];
    float a[8] = {0.f, 0.f, 0.f, 0.f, 0.f, 0.f, 0.f, 0.f};
    agg_body<16>(a, (const uint4*)Z, edges, l, i, d * d, row_ptr[i], row_ptr[i + 1]);
    ((uint4*)Out)[(size_t)i * 16 + l] = pack8(a, bias, l);
}

// F=64: 8 lanes per node, 32 nodes per 256-block
__global__ __launch_bounds__(256) void k_agg64(const ushort* __restrict__ Z,
                                               const float* __restrict__ bias,
                                               const int* __restrict__ row_ptr,
                                               const uint2* __restrict__ edges,
                                               const float* __restrict__ dis,
                                               ushort* __restrict__ Out, int n) {
    int l = threadIdx.x & 7;
    int i = blockIdx.x * 32 + (threadIdx.x >> 3);
    if (i >= n) return;
    float d = dis[i];
    float a[8] = {0.f, 0.f, 0.f, 0.f, 0.f, 0.f, 0.f, 0.f};
    agg_body<8>(a, (const uint4*)Z, edges, l, i, d * d, row_ptr[i], row_ptr[i + 1]);
    ((uint4*)Out)[(size_t)i * 8 + l] = pack8(a, bias, l);
}

// Layer-4 agg (F=64) fused with 64->1 W5 projection: z[i] = relu(agg+b4) . W5
__global__ __launch_bounds__(256) void k_agg64z(const ushort* __restrict__ Z,
                                                const float* __restrict__ bias,
                                                const float* __restrict__ W5,
                                                const int* __restrict__ row_ptr,
                                                const uint2* __restrict__ edges,
                                                const float* __restrict__ dis,
                                                float* __restrict__ z, int n) {
    int l = threadIdx.x & 7;
    int i = blockIdx.x * 32 + (threadIdx.x >> 3);
    if (i >= n) return;
    float d = dis[i];
    float a[8] = {0.f, 0.f, 0.f, 0.f, 0.f, 0.f, 0.f, 0.f};
    agg_body<8>(a, (const uint4*)Z, edges, l, i, d * d, row_ptr[i], row_ptr[i + 1]);
    float4 b0 = *(const float4*)&bias[8 * l];
    float4 b1 = *(const float4*)&bias[8 * l + 4];
    float4 w0 = *(const float4*)&W5[8 * l];
    float4 w1 = *(const float4*)&W5[8 * l + 4];
    float p = fmaxf(a[0] + b0.x, 0.f) * w0.x + fmaxf(a[1] + b0.y, 0.f) * w0.y +
              fmaxf(a[2] + b0.z, 0.f) * w0.z + fmaxf(a[3] + b0.w, 0.f) * w0.w +
              fmaxf(a[4] + b1.x, 0.f) * w1.x + fmaxf(a[5] + b1.y, 0.f) * w1.y +
              fmaxf(a[6] + b1.z, 0.f) * w1.z + fmaxf(a[7] + b1.w, 0.f) * w1.w;
#pragma unroll
    for (int off = 4; off; off >>= 1) p += __shfl_xor(p, off, 64);
    if (l == 0) z[i] = p;
}

// ---------------- fused layer 1: agg3 + 3x128 expand ----------------

__global__ __launch_bounds__(256) void k_l1f(const float* __restrict__ x,
                                             const int* __restrict__ row_ptr,
                                             const uint2* __restrict__ edges,
                                             const float* __restrict__ dis,
                                             const float* __restrict__ W1,
                                             const float* __restrict__ b1,
                                             ushort* __restrict__ A, int n) {
    __shared__ float w[3][128];
    __shared__ float bb[128];
    if (threadIdx.x < 128) {
        w[0][threadIdx.x] = W1[threadIdx.x];
        w[1][threadIdx.x] = W1[128 + threadIdx.x];
        w[2][threadIdx.x] = W1[256 + threadIdx.x];
        bb[threadIdx.x] = b1[threadIdx.x];
    }
    __syncthreads();
    int i = blockIdx.x * NB + threadIdx.x;
    if (i >= n) return;
    float d = dis[i], wgt = d * d;
    float a0 = wgt * x[3 * i], a1 = wgt * x[3 * i + 1], a2 = wgt * x[3 * i + 2];
    int s0 = row_ptr[i], s1 = row_ptr[i + 1];
    int e = s0;
    for (; e + 4 <= s1; e += 4) {
        uint2 e0 = edges[e], e1 = edges[e + 1], e2 = edges[e + 2], e3 = edges[e + 3];
        int j0 = e0.x, j1 = e1.x, j2 = e2.x, j3 = e3.x;
        float n0 = __uint_as_float(e0.y), n1 = __uint_as_float(e1.y);
        float n2 = __uint_as_float(e2.y), n3 = __uint_as_float(e3.y);
        a0 += n0 * x[3 * j0] + n1 * x[3 * j1] + n2 * x[3 * j2] + n3 * x[3 * j3];
        a1 += n0 * x[3 * j0 + 1] + n1 * x[3 * j1 + 1] + n2 * x[3 * j2 + 1] + n3 * x[3 * j3 + 1];
        a2 += n0 * x[3 * j0 + 2] + n1 * x[3 * j1 + 2] + n2 * x[3 * j2 + 2] + n3 * x[3 * j3 + 2];
    }
    for (; e < s1; ++e) {
        uint2 er = edges[e];
        int j = er.x;
        float nv = __uint_as_float(er.y);
        a0 += nv * x[3 * j];
        a1 += nv * x[3 * j + 1];
        a2 += nv * x[3 * j + 2];
    }
    uint4* arow = (uint4*)A + (size_t)i * 16;
#pragma unroll
    for (int f8 = 0; f8 < 16; ++f8) {
        uint32_t ov[4];
#pragma unroll
        for (int p = 0; p < 4; ++p) {
            int f = f8 * 8 + 2 * p;
            float v0 = fmaxf(a0 * w[0][f] + a1 * w[1][f] + a2 * w[2][f] + bb[f], 0.f);
            float v1 = fmaxf(a0 * w[0][f + 1] + a1 * w[1][f + 1] + a2 * w[2][f + 1] + bb[f + 1], 0.f);
            ov[p] = ((uint32_t)f32_to_bf16(v1) << 16) | (uint32_t)f32_to_bf16(v0);
        }
        arow[f8] = make_uint4(ov[0], ov[1], ov[2], ov[3]);
    }
}

// width-1 final aggregation (fp32, + b5)
__global__ void k_agg1(const float* __restrict__ z, const float* __restrict__ b5,
                       const int* __restrict__ row_ptr, const uint2* __restrict__ edges,
                       const float* __restrict__ dis, float* __restrict__ out, int n) {
    int i = blockIdx.x * NB + threadIdx.x;
    if (i >= n) return;
    float d = dis[i];
    float acc = d * d * z[i];
    int s0 = row_ptr[i], s1 = row_ptr[i + 1];
    int e = s0;
    for (; e + 4 <= s1; e += 4) {
        uint2 e0 = edges[e], e1 = edges[e + 1], e2 = edges[e + 2], e3 = edges[e + 3];
        acc += __uint_as_float(e0.y) * z[e0.x] + __uint_as_float(e1.y) * z[e1.x] +
               __uint_as_float(e2.y) * z[e2.x] + __uint_as_float(e3.y) * z[e3.x];
    }
    for (; e < s1; ++e) {
        uint2 er = edges[e];
        acc += __uint_as_float(er.y) * z[er.x];
    }
    out[i] = acc + b5[0];
}

// ---------------- launch ----------------

static inline size_t align_up(size_t x) { return (x + 255) & ~(size_t)255; }

extern "C" void kernel_launch(void* const* d_in, const int* in_sizes, int n_in,
                              void* d_out, int out_size, void* d_ws, size_t ws_size,
                              hipStream_t stream) {
    const int n = in_sizes[0] / 3;   // 100000
    const int e = in_sizes[1] / 2;   // 600000

    const float* x   = (const float*)d_in[0];
    const int*   ei  = (const int*)d_in[1];
    const int*   row = ei;       // sources
    const int*   col = ei + e;   // targets
    const float* W1 = (const float*)d_in[2];  const float* b1 = (const float*)d_in[3];
    const float* W2 = (const float*)d_in[4];  const float* b2 = (const float*)d_in[5];
    const float* W3 = (const float*)d_in[6];  const float* b3 = (const float*)d_in[7];
    const float* W4 = (const float*)d_in[8];  const float* b4 = (const float*)d_in[9];
    const float* W5 = (const float*)d_in[10]; const float* b5 = (const float*)d_in[11];
    float* out = (float*)d_out;

    char* base = (char*)d_ws;
    size_t off = 0;
    auto alloc = [&](size_t bytes) { char* p = base + off; off = align_up(off + bytes); return p; };
    float*  dis        = (float*)alloc((size_t)n * 4);
    int*    counts     = (int*)alloc((size_t)n * 4);
    int*    row_ptr    = (int*)alloc((size_t)(n + 1) * 4);
    int*    cursor     = (int*)alloc((size_t)n * 4);
    int*    blockSums  = (int*)alloc(1024 * 4);
    uint2*  edges      = (uint2*)alloc((size_t)e * 8);
    ushort* A          = (ushort*)alloc((size_t)n * 128 * 2);
    ushort* B          = (ushort*)alloc((size_t)n * 128 * 2);
    float*  zbuf       = (float*)alloc((size_t)n * 4);
    ushort* Wp2        = (ushort*)alloc(128 * 128 * 2);
    ushort* Wp3        = (ushort*)alloc(128 * 64 * 2);
    ushort* Wp4        = (ushort*)alloc(64 * 64 * 2);
    (void)ws_size;

    const int gn = ceil_div(n, NB);        // 391
    const int ge = ceil_div(e, NB);        // 2344
    const int nb1 = gn;                    // <= 512 for scan2
    const int pack_blocks = ceil_div(16384 + 8192 + 4096, NB);  // 112

    // init (zero counts + pack weights) + CSR build
    k_init<<<gn + pack_blocks, NB, 0, stream>>>(counts, n, gn, W2, W3, W4, Wp2, Wp3, Wp4);
    k_count<<<ge, NB, 0, stream>>>(col, e, counts);
    k_scan1<<<nb1, NB, 0, stream>>>(counts, n, row_ptr, blockSums, dis);
    k_scan2<<<1, 512, 0, stream>>>(blockSums, nb1);
    k_scan3<<<ceil_div(n + 1, NB), NB, 0, stream>>>(row_ptr, cursor, blockSums, n, e);
    k_fill<<<ge, NB, 0, stream>>>(row, col, e, cursor, edges, dis);

    // Layer 1 (fused agg3 + expand): A = bf16 relu((A_hat x) @ W1 + b1)
    k_l1f<<<gn, NB, 0, stream>>>(x, row_ptr, edges, dis, W1, b1, A, n);

    // Layer 2
    k_mmfma<128, 128><<<ceil_div(n, 64), 256, 0, stream>>>(A, Wp2, B, n);
    k_agg128<<<ceil_div(n, 16), 256, 0, stream>>>(B, b2, row_ptr, edges, dis, A, n);

    // Layer 3
    k_mmfma<128, 64><<<ceil_div(n, 64), 256, 0, stream>>>(A, Wp3, B, n);
    k_agg64<<<ceil_div(n, 32), 256, 0, stream>>>(B, b3, row_ptr, edges, dis, A, n);

    // Layer 4 (+ fused W5 projection)
    k_mmfma<64, 64><<<ceil_div(n, 64), 256, 0, stream>>>(A, Wp4, B, n);
    k_agg64z<<<ceil_div(n, 32), 256, 0, stream>>>(B, b4, W5, row_ptr, edges, dis, zbuf, n);

    // Layer 5: out = A_hat z + b5
    k_agg1<<<gn, NB, 0, stream>>>(zbuf, b5, row_ptr, edges, dis, out, n);
}

// Round 7
// 252.779 us; speedup vs baseline: 2.6898x; 1.0809x over previous
//
#include <hip/hip_runtime.h>
#include <hip/hip_bf16.h>
#include <stdint.h>

// GCN 5-layer, N=100000, E=600000. bf16 pipeline, bucket-CSR, norm folded
// into GEMM epilogue:
//   B' = dis (.) (H W)   [row scale in GEMM epilogue]
//   out_i = relu(dis_i * (sum_{j in N(i)} B'_j + B'_i) + b)
// => edge record = bare 4B src index (int4 loads), agg = pure sum gather.
// Bucket CSR (CAP=64 slots/node) removes count+scan kernels entirely.

#define NB 256
#define CAP 64

typedef __attribute__((ext_vector_type(8))) short bf16x8;
typedef __attribute__((ext_vector_type(4))) float f32x4;

static __host__ __device__ inline int ceil_div(int a, int b) { return (a + b - 1) / b; }

__device__ inline ushort f32_to_bf16(float x) {   // RNE
    uint32_t u = __float_as_uint(x);
    uint32_t r = (u + 0x7fffu + ((u >> 16) & 1u)) >> 16;
    return (ushort)r;
}
__device__ inline float bf16_lo(uint32_t u) { return __uint_as_float(u << 16); }
__device__ inline float bf16_hi(uint32_t u) { return __uint_as_float(u & 0xffff0000u); }

// ---------------- init: zero cursor + pack weights ----------------

template <int K, int F>
__device__ inline void pack_one(const float* __restrict__ W, ushort* __restrict__ Wp, int id) {
    constexpr int KS = K / 32;
    int j = id & 7;
    int lane = (id >> 3) & 63;
    int ts = id >> 9;
    int s = ts % KS;
    int t = ts / KS;
    int k = s * 32 + ((lane >> 4) << 3) + j;
    int f = t * 16 + (lane & 15);
    Wp[id] = f32_to_bf16(W[k * F + f]);
}

__global__ void k_init(int* __restrict__ cursor, int n, int zero_blocks,
                       const float* __restrict__ W2, const float* __restrict__ W3,
                       const float* __restrict__ W4, ushort* __restrict__ Wp2,
                       ushort* __restrict__ Wp3, ushort* __restrict__ Wp4) {
    int b = blockIdx.x;
    if (b < zero_blocks) {
        int i = b * NB + threadIdx.x;
        if (i < n) cursor[i] = 0;
    } else {
        int id = (b - zero_blocks) * NB + threadIdx.x;
        if (id < 16384) pack_one<128, 128>(W2, Wp2, id);
        else if (id < 24576) pack_one<128, 64>(W3, Wp3, id - 16384);
        else if (id < 28672) pack_one<64, 64>(W4, Wp4, id - 24576);
    }
}

// ---------------- bucket CSR: one atomic + one 4B store per edge ----------------

__global__ void k_fillb(const int* __restrict__ row, const int* __restrict__ col, int e,
                        int* __restrict__ cursor, int* __restrict__ bucket) {
    int i = blockIdx.x * NB + threadIdx.x;
    if (i < e) {
        int c = col[i], r = row[i];
        int slot = atomicAdd(&cursor[c], 1);          // cursor becomes degree
        bucket[(size_t)c * CAP + slot] = r;
    }
}

// dis = rsqrt(deg+1); xs = dis * x (stride-4 for aligned float4 gathers)
__global__ void k_dis(const int* __restrict__ cnt, const float* __restrict__ x,
                      float* __restrict__ dis, float4* __restrict__ xs4, int n) {
    int i = blockIdx.x * NB + threadIdx.x;
    if (i >= n) return;
    float d = rsqrtf((float)(cnt[i] + 1));
    dis[i] = d;
    xs4[i] = make_float4(d * x[3 * i], d * x[3 * i + 1], d * x[3 * i + 2], 0.f);
}

// ---------------- fused layer 1: sum-gather xs + 3x128 expand ----------------

__global__ __launch_bounds__(256) void k_l1f(const float4* __restrict__ xs4,
                                             const int* __restrict__ cnt,
                                             const int* __restrict__ bucket,
                                             const float* __restrict__ dis,
                                             const float* __restrict__ W1,
                                             const float* __restrict__ b1,
                                             ushort* __restrict__ A, int n) {
    __shared__ float w[512];   // W1 (384) + b1 (128)
    for (int t = threadIdx.x; t < 512; t += 256)
        w[t] = (t < 384) ? W1[t] : b1[t - 384];
    __syncthreads();
    int i = blockIdx.x * NB + threadIdx.x;
    if (i >= n) return;
    float4 self = xs4[i];
    float a0 = self.x, a1 = self.y, a2 = self.z;
    int deg = cnt[i];
    const int* bk = bucket + (size_t)i * CAP;
    int e = 0;
    for (; e + 4 <= deg; e += 4) {
        int4 j4 = *(const int4*)(bk + e);
        float4 v0 = xs4[j4.x], v1 = xs4[j4.y], v2 = xs4[j4.z], v3 = xs4[j4.w];
        a0 += v0.x + v1.x + v2.x + v3.x;
        a1 += v0.y + v1.y + v2.y + v3.y;
        a2 += v0.z + v1.z + v2.z + v3.z;
    }
    for (; e < deg; ++e) {
        float4 v = xs4[bk[e]];
        a0 += v.x; a1 += v.y; a2 += v.z;
    }
    float d = dis[i];
    a0 *= d; a1 *= d; a2 *= d;
    uint4* arow = (uint4*)A + (size_t)i * 16;
#pragma unroll
    for (int f8 = 0; f8 < 16; ++f8) {
        uint32_t ov[4];
#pragma unroll
        for (int q = 0; q < 4; ++q) {
            int f = f8 * 8 + 2 * q;
            float v0 = fmaxf(a0 * w[f] + a1 * w[128 + f] + a2 * w[256 + f] + w[384 + f], 0.f);
            float v1 = fmaxf(a0 * w[f + 1] + a1 * w[128 + f + 1] + a2 * w[256 + f + 1] + w[384 + f + 1], 0.f);
            ov[q] = ((uint32_t)f32_to_bf16(v1) << 16) | (uint32_t)f32_to_bf16(v0);
        }
        arow[f8] = make_uint4(ov[0], ov[1], ov[2], ov[3]);
    }
}

// ---------------- MFMA GEMM: Z = dis (.) (H @ W), bf16 in/out ----------------

template <int K, int F>
__global__ __launch_bounds__(256) void k_mmfma(const ushort* __restrict__ H,
                                               const ushort* __restrict__ Wp,
                                               const float* __restrict__ dis,
                                               ushort* __restrict__ Z, int n) {
    constexpr int KS = K / 32;
    constexpr int FT = F / 16;
    int wid = threadIdx.x >> 6;
    int lane = threadIdx.x & 63;
    int node0 = blockIdx.x * 64 + wid * 16;
    int m = lane & 15;
    int quad = lane >> 4;
    int arow = node0 + m;
    if (arow >= n) arow = n - 1;
    const bf16x8* aptr = (const bf16x8*)(H + (size_t)arow * K + quad * 8);
    bf16x8 a[KS];
#pragma unroll
    for (int s = 0; s < KS; ++s) a[s] = aptr[s * 4];
    float dsc[4];
#pragma unroll
    for (int r = 0; r < 4; ++r) {
        int node = node0 + quad * 4 + r;
        dsc[r] = (node < n) ? dis[node] : 0.f;
    }
    const bf16x8* bp = (const bf16x8*)Wp;
#pragma unroll 2
    for (int t = 0; t < FT; ++t) {
        f32x4 acc = {0.f, 0.f, 0.f, 0.f};
#pragma unroll
        for (int s = 0; s < KS; ++s)
            acc = __builtin_amdgcn_mfma_f32_16x16x32_bf16(a[s], bp[(t * KS + s) * 64 + lane], acc, 0, 0, 0);
        int feat = t * 16 + m;
#pragma unroll
        for (int r = 0; r < 4; ++r) {
            int node = node0 + quad * 4 + r;
            if (node < n) Z[(size_t)node * F + feat] = f32_to_bf16(acc[r] * dsc[r]);
        }
    }
}

// ---------------- aggregation: pure sum gather (bf16), fp32 accum ----------------

__device__ inline void add8(float (&a)[8], uint4 v) {
    a[0] += bf16_lo(v.x);
    a[1] += bf16_hi(v.x);
    a[2] += bf16_lo(v.y);
    a[3] += bf16_hi(v.y);
    a[4] += bf16_lo(v.z);
    a[5] += bf16_hi(v.z);
    a[6] += bf16_lo(v.w);
    a[7] += bf16_hi(v.w);
}

// L lanes per node, row = L uint4; x4 edge unroll via int4 index loads
template <int L>
__device__ inline void agg_sum(float (&a)[8], const uint4* __restrict__ Zq,
                               const int* __restrict__ bk, int deg, int l, int i) {
    add8(a, Zq[(size_t)i * L + l]);   // self
    int e = 0;
    for (; e + 4 <= deg; e += 4) {
        int4 j4 = *(const int4*)(bk + e);
        uint4 v0 = Zq[(size_t)j4.x * L + l];
        uint4 v1 = Zq[(size_t)j4.y * L + l];
        uint4 v2 = Zq[(size_t)j4.z * L + l];
        uint4 v3 = Zq[(size_t)j4.w * L + l];
        add8(a, v0);
        add8(a, v1);
        add8(a, v2);
        add8(a, v3);
    }
    for (; e < deg; ++e) add8(a, Zq[(size_t)bk[e] * L + l]);
}

__device__ inline uint4 pack8s(const float (&a)[8], float d, const float* __restrict__ bias, int l) {
    float4 b0 = *(const float4*)&bias[8 * l];
    float4 b1 = *(const float4*)&bias[8 * l + 4];
    float r0 = fmaxf(a[0] * d + b0.x, 0.f), r1 = fmaxf(a[1] * d + b0.y, 0.f);
    float r2 = fmaxf(a[2] * d + b0.z, 0.f), r3 = fmaxf(a[3] * d + b0.w, 0.f);
    float r4 = fmaxf(a[4] * d + b1.x, 0.f), r5 = fmaxf(a[5] * d + b1.y, 0.f);
    float r6 = fmaxf(a[6] * d + b1.z, 0.f), r7 = fmaxf(a[7] * d + b1.w, 0.f);
    uint4 o;
    o.x = ((uint32_t)f32_to_bf16(r1) << 16) | (uint32_t)f32_to_bf16(r0);
    o.y = ((uint32_t)f32_to_bf16(r3) << 16) | (uint32_t)f32_to_bf16(r2);
    o.z = ((uint32_t)f32_to_bf16(r5) << 16) | (uint32_t)f32_to_bf16(r4);
    o.w = ((uint32_t)f32_to_bf16(r7) << 16) | (uint32_t)f32_to_bf16(r6);
    return o;
}

// F=128: 16 lanes per node
__global__ __launch_bounds__(256) void k_agg128(const ushort* __restrict__ Z,
                                                const float* __restrict__ bias,
                                                const int* __restrict__ cnt,
                                                const int* __restrict__ bucket,
                                                const float* __restrict__ dis,
                                                ushort* __restrict__ Out, int n) {
    int l = threadIdx.x & 15;
    int i = blockIdx.x * 16 + (threadIdx.x >> 4);
    if (i >= n) return;
    float a[8] = {0.f, 0.f, 0.f, 0.f, 0.f, 0.f, 0.f, 0.f};
    agg_sum<16>(a, (const uint4*)Z, bucket + (size_t)i * CAP, cnt[i], l, i);
    ((uint4*)Out)[(size_t)i * 16 + l] = pack8s(a, dis[i], bias, l);
}

// F=64: 8 lanes per node
__global__ __launch_bounds__(256) void k_agg64(const ushort* __restrict__ Z,
                                               const float* __restrict__ bias,
                                               const int* __restrict__ cnt,
                                               const int* __restrict__ bucket,
                                               const float* __restrict__ dis,
                                               ushort* __restrict__ Out, int n) {
    int l = threadIdx.x & 7;
    int i = blockIdx.x * 32 + (threadIdx.x >> 3);
    if (i >= n) return;
    float a[8] = {0.f, 0.f, 0.f, 0.f, 0.f, 0.f, 0.f, 0.f};
    agg_sum<8>(a, (const uint4*)Z, bucket + (size_t)i * CAP, cnt[i], l, i);
    ((uint4*)Out)[(size_t)i * 8 + l] = pack8s(a, dis[i], bias, l);
}

// Layer-4 agg fused with 64->1 W5 projection; stores zbuf = dis_i * proj_i
__global__ __launch_bounds__(256) void k_agg64z(const ushort* __restrict__ Z,
                                                const float* __restrict__ bias,
                                                const float* __restrict__ W5,
                                                const int* __restrict__ cnt,
                                                const int* __restrict__ bucket,
                                                const float* __restrict__ dis,
                                                float* __restrict__ zbuf, int n) {
    int l = threadIdx.x & 7;
    int i = blockIdx.x * 32 + (threadIdx.x >> 3);
    if (i >= n) return;
    float a[8] = {0.f, 0.f, 0.f, 0.f, 0.f, 0.f, 0.f, 0.f};
    agg_sum<8>(a, (const uint4*)Z, bucket + (size_t)i * CAP, cnt[i], l, i);
    float d = dis[i];
    float4 b0 = *(const float4*)&bias[8 * l];
    float4 b1 = *(const float4*)&bias[8 * l + 4];
    float4 w0 = *(const float4*)&W5[8 * l];
    float4 w1 = *(const float4*)&W5[8 * l + 4];
    float p = fmaxf(a[0] * d + b0.x, 0.f) * w0.x + fmaxf(a[1] * d + b0.y, 0.f) * w0.y +
              fmaxf(a[2] * d + b0.z, 0.f) * w0.z + fmaxf(a[3] * d + b0.w, 0.f) * w0.w +
              fmaxf(a[4] * d + b1.x, 0.f) * w1.x + fmaxf(a[5] * d + b1.y, 0.f) * w1.y +
              fmaxf(a[6] * d + b1.z, 0.f) * w1.z + fmaxf(a[7] * d + b1.w, 0.f) * w1.w;
#pragma unroll
    for (int off = 4; off; off >>= 1) p += __shfl_xor(p, off, 64);
    if (l == 0) zbuf[i] = d * p;
}

// final: out_i = dis_i * (sum zbuf_j + zbuf_i) + b5
__global__ void k_agg1(const float* __restrict__ zbuf, const float* __restrict__ b5,
                       const int* __restrict__ cnt, const int* __restrict__ bucket,
                       const float* __restrict__ dis, float* __restrict__ out, int n) {
    int i = blockIdx.x * NB + threadIdx.x;
    if (i >= n) return;
    float acc = zbuf[i];
    int deg = cnt[i];
    const int* bk = bucket + (size_t)i * CAP;
    int e = 0;
    for (; e + 4 <= deg; e += 4) {
        int4 j4 = *(const int4*)(bk + e);
        acc += zbuf[j4.x] + zbuf[j4.y] + zbuf[j4.z] + zbuf[j4.w];
    }
    for (; e < deg; ++e) acc += zbuf[bk[e]];
    out[i] = dis[i] * acc + b5[0];
}

// ---------------- launch ----------------

static inline size_t align_up(size_t x) { return (x + 255) & ~(size_t)255; }

extern "C" void kernel_launch(void* const* d_in, const int* in_sizes, int n_in,
                              void* d_out, int out_size, void* d_ws, size_t ws_size,
                              hipStream_t stream) {
    const int n = in_sizes[0] / 3;   // 100000
    const int e = in_sizes[1] / 2;   // 600000

    const float* x   = (const float*)d_in[0];
    const int*   ei  = (const int*)d_in[1];
    const int*   row = ei;       // sources
    const int*   col = ei + e;   // targets
    const float* W1 = (const float*)d_in[2];  const float* b1 = (const float*)d_in[3];
    const float* W2 = (const float*)d_in[4];  const float* b2 = (const float*)d_in[5];
    const float* W3 = (const float*)d_in[6];  const float* b3 = (const float*)d_in[7];
    const float* W4 = (const float*)d_in[8];  const float* b4 = (const float*)d_in[9];
    const float* W5 = (const float*)d_in[10]; const float* b5 = (const float*)d_in[11];
    float* out = (float*)d_out;

    char* base = (char*)d_ws;
    size_t off = 0;
    auto alloc = [&](size_t bytes) { char* p = base + off; off = align_up(off + bytes); return p; };
    int*    cursor = (int*)alloc((size_t)n * 4);          // becomes degree
    float*  dis    = (float*)alloc((size_t)n * 4);
    float4* xs4    = (float4*)alloc((size_t)n * 16);
    int*    bucket = (int*)alloc((size_t)n * CAP * 4);    // 25.6 MB
    ushort* A      = (ushort*)alloc((size_t)n * 128 * 2);
    ushort* B      = (ushort*)alloc((size_t)n * 128 * 2);
    float*  zbuf   = (float*)alloc((size_t)n * 4);
    ushort* Wp2    = (ushort*)alloc(128 * 128 * 2);
    ushort* Wp3    = (ushort*)alloc(128 * 64 * 2);
    ushort* Wp4    = (ushort*)alloc(64 * 64 * 2);
    (void)ws_size;

    const int gn = ceil_div(n, NB);        // 391
    const int ge = ceil_div(e, NB);        // 2344
    const int pack_blocks = ceil_div(16384 + 8192 + 4096, NB);  // 112

    // CSR (bucket) build: 3 kernels, no scan
    k_init<<<gn + pack_blocks, NB, 0, stream>>>(cursor, n, gn, W2, W3, W4, Wp2, Wp3, Wp4);
    k_fillb<<<ge, NB, 0, stream>>>(row, col, e, cursor, bucket);
    k_dis<<<gn, NB, 0, stream>>>(cursor, x, dis, xs4, n);

    // Layer 1 (fused sum-agg + 3x128 expand)
    k_l1f<<<gn, NB, 0, stream>>>(xs4, cursor, bucket, dis, W1, b1, A, n);

    // Layer 2
    k_mmfma<128, 128><<<ceil_div(n, 64), 256, 0, stream>>>(A, Wp2, dis, B, n);
    k_agg128<<<ceil_div(n, 16), 256, 0, stream>>>(B, b2, cursor, bucket, dis, A, n);

    // Layer 3
    k_mmfma<128, 64><<<ceil_div(n, 64), 256, 0, stream>>>(A, Wp3, dis, B, n);
    k_agg64<<<ceil_div(n, 32), 256, 0, stream>>>(B, b3, cursor, bucket, dis, A, n);

    // Layer 4 (+ fused W5 projection)
    k_mmfma<64, 64><<<ceil_div(n, 64), 256, 0, stream>>>(A, Wp4, dis, B, n);
    k_agg64z<<<ceil_div(n, 32), 256, 0, stream>>>(B, b4, W5, cursor, bucket, dis, zbuf, n);

    // Layer 5
    k_agg1<<<gn, NB, 0, stream>>>(zbuf, b5, cursor, bucket, dis, out, n);
}

// Round 8
// 226.606 us; speedup vs baseline: 3.0004x; 1.1155x over previous
//
#include <hip/hip_runtime.h>
#include <hip/hip_bf16.h>
#include <stdint.h>

// GCN 5-layer, N=100000, E=600000. bf16 pipeline, bucket-CSR, norm folded
// into GEMM epilogue. Round-8:
//  - k_fillb unrolled x4 (4 independent atomic chains/thread).
//  - agg+GEMM fused per 64-node tile via padded LDS staging:
//      k_aggmm<128,64> (layer2-agg + layer3-GEMM), k_aggmm<64,64> (l3-agg + l4-GEMM).

#define NB 256
#define CAP 64

typedef __attribute__((ext_vector_type(8))) short bf16x8;
typedef __attribute__((ext_vector_type(4))) float f32x4;

static __host__ __device__ inline int ceil_div(int a, int b) { return (a + b - 1) / b; }

__device__ inline ushort f32_to_bf16(float x) {   // RNE
    uint32_t u = __float_as_uint(x);
    uint32_t r = (u + 0x7fffu + ((u >> 16) & 1u)) >> 16;
    return (ushort)r;
}
__device__ inline float bf16_lo(uint32_t u) { return __uint_as_float(u << 16); }
__device__ inline float bf16_hi(uint32_t u) { return __uint_as_float(u & 0xffff0000u); }

// ---------------- init: zero cursor + pack weights ----------------

template <int K, int F>
__device__ inline void pack_one(const float* __restrict__ W, ushort* __restrict__ Wp, int id) {
    constexpr int KS = K / 32;
    int j = id & 7;
    int lane = (id >> 3) & 63;
    int ts = id >> 9;
    int s = ts % KS;
    int t = ts / KS;
    int k = s * 32 + ((lane >> 4) << 3) + j;
    int f = t * 16 + (lane & 15);
    Wp[id] = f32_to_bf16(W[k * F + f]);
}

__global__ void k_init(int* __restrict__ cursor, int n, int zero_blocks,
                       const float* __restrict__ W2, const float* __restrict__ W3,
                       const float* __restrict__ W4, ushort* __restrict__ Wp2,
                       ushort* __restrict__ Wp3, ushort* __restrict__ Wp4) {
    int b = blockIdx.x;
    if (b < zero_blocks) {
        int i = b * NB + threadIdx.x;
        if (i < n) cursor[i] = 0;
    } else {
        int id = (b - zero_blocks) * NB + threadIdx.x;
        if (id < 16384) pack_one<128, 128>(W2, Wp2, id);
        else if (id < 24576) pack_one<128, 64>(W3, Wp3, id - 16384);
        else if (id < 28672) pack_one<64, 64>(W4, Wp4, id - 24576);
    }
}

// ---------------- bucket CSR fill: x4 unrolled for atomic MLP ----------------

__global__ void k_fillb(const int* __restrict__ row, const int* __restrict__ col, int e,
                        int* __restrict__ cursor, int* __restrict__ bucket) {
    int T = (e + 3) >> 2;
    int t = blockIdx.x * NB + threadIdx.x;
    int i0 = t, i1 = t + T, i2 = t + 2 * T, i3 = t + 3 * T;
    if (i3 < e) {   // i0<i1<i2<i3 => all valid
        int c0 = col[i0], c1 = col[i1], c2 = col[i2], c3 = col[i3];
        int r0 = row[i0], r1 = row[i1], r2 = row[i2], r3 = row[i3];
        int s0 = atomicAdd(&cursor[c0], 1);
        int s1 = atomicAdd(&cursor[c1], 1);
        int s2 = atomicAdd(&cursor[c2], 1);
        int s3 = atomicAdd(&cursor[c3], 1);
        bucket[(size_t)c0 * CAP + s0] = r0;
        bucket[(size_t)c1 * CAP + s1] = r1;
        bucket[(size_t)c2 * CAP + s2] = r2;
        bucket[(size_t)c3 * CAP + s3] = r3;
    } else {
        int idx[4] = {i0, i1, i2, i3};
#pragma unroll
        for (int k = 0; k < 4; ++k) {
            int i = idx[k];
            if (i < e) {
                int c = col[i], r = row[i];
                int s = atomicAdd(&cursor[c], 1);
                bucket[(size_t)c * CAP + s] = r;
            }
        }
    }
}

// dis = rsqrt(deg+1); xs = dis * x (stride-4 for aligned float4 gathers)
__global__ void k_dis(const int* __restrict__ cnt, const float* __restrict__ x,
                      float* __restrict__ dis, float4* __restrict__ xs4, int n) {
    int i = blockIdx.x * NB + threadIdx.x;
    if (i >= n) return;
    float d = rsqrtf((float)(cnt[i] + 1));
    dis[i] = d;
    xs4[i] = make_float4(d * x[3 * i], d * x[3 * i + 1], d * x[3 * i + 2], 0.f);
}

// ---------------- fused layer 1: sum-gather xs + 3x128 expand ----------------

__global__ __launch_bounds__(256) void k_l1f(const float4* __restrict__ xs4,
                                             const int* __restrict__ cnt,
                                             const int* __restrict__ bucket,
                                             const float* __restrict__ dis,
                                             const float* __restrict__ W1,
                                             const float* __restrict__ b1,
                                             ushort* __restrict__ A, int n) {
    __shared__ float w[512];   // W1 (384) + b1 (128)
    for (int t = threadIdx.x; t < 512; t += 256)
        w[t] = (t < 384) ? W1[t] : b1[t - 384];
    __syncthreads();
    int i = blockIdx.x * NB + threadIdx.x;
    if (i >= n) return;
    float4 self = xs4[i];
    float a0 = self.x, a1 = self.y, a2 = self.z;
    int deg = cnt[i];
    const int* bk = bucket + (size_t)i * CAP;
    int e = 0;
    for (; e + 4 <= deg; e += 4) {
        int4 j4 = *(const int4*)(bk + e);
        float4 v0 = xs4[j4.x], v1 = xs4[j4.y], v2 = xs4[j4.z], v3 = xs4[j4.w];
        a0 += v0.x + v1.x + v2.x + v3.x;
        a1 += v0.y + v1.y + v2.y + v3.y;
        a2 += v0.z + v1.z + v2.z + v3.z;
    }
    for (; e < deg; ++e) {
        float4 v = xs4[bk[e]];
        a0 += v.x; a1 += v.y; a2 += v.z;
    }
    float d = dis[i];
    a0 *= d; a1 *= d; a2 *= d;
    uint4* arow = (uint4*)A + (size_t)i * 16;
#pragma unroll
    for (int f8 = 0; f8 < 16; ++f8) {
        uint32_t ov[4];
#pragma unroll
        for (int q = 0; q < 4; ++q) {
            int f = f8 * 8 + 2 * q;
            float v0 = fmaxf(a0 * w[f] + a1 * w[128 + f] + a2 * w[256 + f] + w[384 + f], 0.f);
            float v1 = fmaxf(a0 * w[f + 1] + a1 * w[128 + f + 1] + a2 * w[256 + f + 1] + w[384 + f + 1], 0.f);
            ov[q] = ((uint32_t)f32_to_bf16(v1) << 16) | (uint32_t)f32_to_bf16(v0);
        }
        arow[f8] = make_uint4(ov[0], ov[1], ov[2], ov[3]);
    }
}

// ---------------- standalone MFMA GEMM: Z = dis (.) (H @ W) ----------------

template <int K, int F>
__global__ __launch_bounds__(256) void k_mmfma(const ushort* __restrict__ H,
                                               const ushort* __restrict__ Wp,
                                               const float* __restrict__ dis,
                                               ushort* __restrict__ Z, int n) {
    constexpr int KS = K / 32;
    constexpr int FT = F / 16;
    int wid = threadIdx.x >> 6;
    int lane = threadIdx.x & 63;
    int node0 = blockIdx.x * 64 + wid * 16;
    int m = lane & 15;
    int quad = lane >> 4;
    int arow = node0 + m;
    if (arow >= n) arow = n - 1;
    const bf16x8* aptr = (const bf16x8*)(H + (size_t)arow * K + quad * 8);
    bf16x8 a[KS];
#pragma unroll
    for (int s = 0; s < KS; ++s) a[s] = aptr[s * 4];
    float dsc[4];
#pragma unroll
    for (int r = 0; r < 4; ++r) {
        int node = node0 + quad * 4 + r;
        dsc[r] = (node < n) ? dis[node] : 0.f;
    }
    const bf16x8* bp = (const bf16x8*)Wp;
#pragma unroll 2
    for (int t = 0; t < FT; ++t) {
        f32x4 acc = {0.f, 0.f, 0.f, 0.f};
#pragma unroll
        for (int s = 0; s < KS; ++s)
            acc = __builtin_amdgcn_mfma_f32_16x16x32_bf16(a[s], bp[(t * KS + s) * 64 + lane], acc, 0, 0, 0);
        int feat = t * 16 + m;
#pragma unroll
        for (int r = 0; r < 4; ++r) {
            int node = node0 + quad * 4 + r;
            if (node < n) Z[(size_t)node * F + feat] = f32_to_bf16(acc[r] * dsc[r]);
        }
    }
}

// ---------------- aggregation primitives (pure sum gather, fp32 accum) ----------------

__device__ inline void add8(float (&a)[8], uint4 v) {
    a[0] += bf16_lo(v.x);
    a[1] += bf16_hi(v.x);
    a[2] += bf16_lo(v.y);
    a[3] += bf16_hi(v.y);
    a[4] += bf16_lo(v.z);
    a[5] += bf16_hi(v.z);
    a[6] += bf16_lo(v.w);
    a[7] += bf16_hi(v.w);
}

template <int L>
__device__ inline void agg_sum(float (&a)[8], const uint4* __restrict__ Zq,
                               const int* __restrict__ bk, int deg, int l, int i) {
    add8(a, Zq[(size_t)i * L + l]);   // self
    int e = 0;
    for (; e + 4 <= deg; e += 4) {
        int4 j4 = *(const int4*)(bk + e);
        uint4 v0 = Zq[(size_t)j4.x * L + l];
        uint4 v1 = Zq[(size_t)j4.y * L + l];
        uint4 v2 = Zq[(size_t)j4.z * L + l];
        uint4 v3 = Zq[(size_t)j4.w * L + l];
        add8(a, v0);
        add8(a, v1);
        add8(a, v2);
        add8(a, v3);
    }
    for (; e < deg; ++e) add8(a, Zq[(size_t)bk[e] * L + l]);
}

__device__ inline uint4 pack8s(const float (&a)[8], float d, const float* __restrict__ bias, int l) {
    float4 b0 = *(const float4*)&bias[8 * l];
    float4 b1 = *(const float4*)&bias[8 * l + 4];
    float r0 = fmaxf(a[0] * d + b0.x, 0.f), r1 = fmaxf(a[1] * d + b0.y, 0.f);
    float r2 = fmaxf(a[2] * d + b0.z, 0.f), r3 = fmaxf(a[3] * d + b0.w, 0.f);
    float r4 = fmaxf(a[4] * d + b1.x, 0.f), r5 = fmaxf(a[5] * d + b1.y, 0.f);
    float r6 = fmaxf(a[6] * d + b1.z, 0.f), r7 = fmaxf(a[7] * d + b1.w, 0.f);
    uint4 o;
    o.x = ((uint32_t)f32_to_bf16(r1) << 16) | (uint32_t)f32_to_bf16(r0);
    o.y = ((uint32_t)f32_to_bf16(r3) << 16) | (uint32_t)f32_to_bf16(r2);
    o.z = ((uint32_t)f32_to_bf16(r5) << 16) | (uint32_t)f32_to_bf16(r4);
    o.w = ((uint32_t)f32_to_bf16(r7) << 16) | (uint32_t)f32_to_bf16(r6);
    return o;
}

// ---------------- fused agg + GEMM: per 64-node tile via LDS ----------------
// Agg FIN-wide rows of this block's 64 nodes into LDS (padded +8 ushorts =>
// 2-way bank aliasing only, free), then 4 waves run the FIN->FOUT MFMA.

template <int FIN, int FOUT>
__global__ __launch_bounds__(256) void k_aggmm(const ushort* __restrict__ Zin,
                                               const float* __restrict__ bias,
                                               const int* __restrict__ cnt,
                                               const int* __restrict__ bucket,
                                               const float* __restrict__ dis,
                                               const ushort* __restrict__ Wp,
                                               ushort* __restrict__ Zout, int n) {
    constexpr int L = FIN / 8;          // lanes per node in agg phase
    constexpr int GROUPS = 256 / L;     // node groups per pass
    constexpr int PASSES = 64 / GROUPS;
    __shared__ ushort tileA[64][FIN + 8];
    int node0 = blockIdx.x * 64;

    // ---- agg phase ----
    {
        int l = threadIdx.x & (L - 1);
        int g = threadIdx.x / L;
#pragma unroll
        for (int pass = 0; pass < PASSES; ++pass) {
            int local = pass * GROUPS + g;
            int i = node0 + local;
            if (i < n) {
                float a[8] = {0.f, 0.f, 0.f, 0.f, 0.f, 0.f, 0.f, 0.f};
                agg_sum<L>(a, (const uint4*)Zin, bucket + (size_t)i * CAP, cnt[i], l, i);
                *(uint4*)&tileA[local][l * 8] = pack8s(a, dis[i], bias, l);
            }
        }
    }
    __syncthreads();

    // ---- MFMA phase ----
    constexpr int KS = FIN / 32;
    constexpr int FT = FOUT / 16;
    int wid = threadIdx.x >> 6;
    int lane = threadIdx.x & 63;
    int m = lane & 15;
    int quad = lane >> 4;
    int tbase = wid * 16;
    bf16x8 a[KS];
#pragma unroll
    for (int s = 0; s < KS; ++s)
        a[s] = *(const bf16x8*)&tileA[tbase + m][s * 32 + quad * 8];
    float dsc[4];
#pragma unroll
    for (int r = 0; r < 4; ++r) {
        int node = node0 + tbase + quad * 4 + r;
        dsc[r] = (node < n) ? dis[node] : 0.f;
    }
    const bf16x8* bp = (const bf16x8*)Wp;
#pragma unroll
    for (int t = 0; t < FT; ++t) {
        f32x4 acc = {0.f, 0.f, 0.f, 0.f};
#pragma unroll
        for (int s = 0; s < KS; ++s)
            acc = __builtin_amdgcn_mfma_f32_16x16x32_bf16(a[s], bp[(t * KS + s) * 64 + lane], acc, 0, 0, 0);
        int feat = t * 16 + m;
#pragma unroll
        for (int r = 0; r < 4; ++r) {
            int node = node0 + tbase + quad * 4 + r;
            if (node < n) Zout[(size_t)node * FOUT + feat] = f32_to_bf16(acc[r] * dsc[r]);
        }
    }
}

// Layer-4 agg fused with 64->1 W5 projection; stores zbuf = dis_i * proj_i
__global__ __launch_bounds__(256) void k_agg64z(const ushort* __restrict__ Z,
                                                const float* __restrict__ bias,
                                                const float* __restrict__ W5,
                                                const int* __restrict__ cnt,
                                                const int* __restrict__ bucket,
                                                const float* __restrict__ dis,
                                                float* __restrict__ zbuf, int n) {
    int l = threadIdx.x & 7;
    int i = blockIdx.x * 32 + (threadIdx.x >> 3);
    if (i >= n) return;
    float a[8] = {0.f, 0.f, 0.f, 0.f, 0.f, 0.f, 0.f, 0.f};
    agg_sum<8>(a, (const uint4*)Z, bucket + (size_t)i * CAP, cnt[i], l, i);
    float d = dis[i];
    float4 b0 = *(const float4*)&bias[8 * l];
    float4 b1 = *(const float4*)&bias[8 * l + 4];
    float4 w0 = *(const float4*)&W5[8 * l];
    float4 w1 = *(const float4*)&W5[8 * l + 4];
    float p = fmaxf(a[0] * d + b0.x, 0.f) * w0.x + fmaxf(a[1] * d + b0.y, 0.f) * w0.y +
              fmaxf(a[2] * d + b0.z, 0.f) * w0.z + fmaxf(a[3] * d + b0.w, 0.f) * w0.w +
              fmaxf(a[4] * d + b1.x, 0.f) * w1.x + fmaxf(a[5] * d + b1.y, 0.f) * w1.y +
              fmaxf(a[6] * d + b1.z, 0.f) * w1.z + fmaxf(a[7] * d + b1.w, 0.f) * w1.w;
#pragma unroll
    for (int off = 4; off; off >>= 1) p += __shfl_xor(p, off, 64);
    if (l == 0) zbuf[i] = d * p;
}

// final: out_i = dis_i * (sum zbuf_j + zbuf_i) + b5
__global__ void k_agg1(const float* __restrict__ zbuf, const float* __restrict__ b5,
                       const int* __restrict__ cnt, const int* __restrict__ bucket,
                       const float* __restrict__ dis, float* __restrict__ out, int n) {
    int i = blockIdx.x * NB + threadIdx.x;
    if (i >= n) return;
    float acc = zbuf[i];
    int deg = cnt[i];
    const int* bk = bucket + (size_t)i * CAP;
    int e = 0;
    for (; e + 4 <= deg; e += 4) {
        int4 j4 = *(const int4*)(bk + e);
        acc += zbuf[j4.x] + zbuf[j4.y] + zbuf[j4.z] + zbuf[j4.w];
    }
    for (; e < deg; ++e) acc += zbuf[bk[e]];
    out[i] = dis[i] * acc + b5[0];
}

// ---------------- launch ----------------

static inline size_t align_up(size_t x) { return (x + 255) & ~(size_t)255; }

extern "C" void kernel_launch(void* const* d_in, const int* in_sizes, int n_in,
                              void* d_out, int out_size, void* d_ws, size_t ws_size,
                              hipStream_t stream) {
    const int n = in_sizes[0] / 3;   // 100000
    const int e = in_sizes[1] / 2;   // 600000

    const float* x   = (const float*)d_in[0];
    const int*   ei  = (const int*)d_in[1];
    const int*   row = ei;       // sources
    const int*   col = ei + e;   // targets
    const float* W1 = (const float*)d_in[2];  const float* b1 = (const float*)d_in[3];
    const float* W2 = (const float*)d_in[4];  const float* b2 = (const float*)d_in[5];
    const float* W3 = (const float*)d_in[6];  const float* b3 = (const float*)d_in[7];
    const float* W4 = (const float*)d_in[8];  const float* b4 = (const float*)d_in[9];
    const float* W5 = (const float*)d_in[10]; const float* b5 = (const float*)d_in[11];
    float* out = (float*)d_out;

    char* base = (char*)d_ws;
    size_t off = 0;
    auto alloc = [&](size_t bytes) { char* p = base + off; off = align_up(off + bytes); return p; };
    int*    cursor = (int*)alloc((size_t)n * 4);          // becomes degree
    float*  dis    = (float*)alloc((size_t)n * 4);
    float4* xs4    = (float4*)alloc((size_t)n * 16);
    int*    bucket = (int*)alloc((size_t)n * CAP * 4);    // 25.6 MB
    ushort* A      = (ushort*)alloc((size_t)n * 128 * 2);
    ushort* B      = (ushort*)alloc((size_t)n * 128 * 2);
    float*  zbuf   = (float*)alloc((size_t)n * 4);
    ushort* Wp2    = (ushort*)alloc(128 * 128 * 2);
    ushort* Wp3    = (ushort*)alloc(128 * 64 * 2);
    ushort* Wp4    = (ushort*)alloc(64 * 64 * 2);
    (void)ws_size;

    const int gn = ceil_div(n, NB);        // 391
    const int pack_blocks = ceil_div(16384 + 8192 + 4096, NB);  // 112

    // bucket CSR build
    k_init<<<gn + pack_blocks, NB, 0, stream>>>(cursor, n, gn, W2, W3, W4, Wp2, Wp3, Wp4);
    k_fillb<<<ceil_div(ceil_div(e, 4), NB), NB, 0, stream>>>(row, col, e, cursor, bucket);
    k_dis<<<gn, NB, 0, stream>>>(cursor, x, dis, xs4, n);

    // Layer 1 (fused sum-agg + 3x128 expand)
    k_l1f<<<gn, NB, 0, stream>>>(xs4, cursor, bucket, dis, W1, b1, A, n);

    // Layer 2 GEMM: B = dis (.) (A @ W2)
    k_mmfma<128, 128><<<ceil_div(n, 64), 256, 0, stream>>>(A, Wp2, dis, B, n);

    // Layer 2 agg + Layer 3 GEMM (fused): A = dis (.) (relu-agg(B,b2) @ W3)
    k_aggmm<128, 64><<<ceil_div(n, 64), 256, 0, stream>>>(B, b2, cursor, bucket, dis, Wp3, A, n);

    // Layer 3 agg + Layer 4 GEMM (fused): B = dis (.) (relu-agg(A,b3) @ W4)
    k_aggmm<64, 64><<<ceil_div(n, 64), 256, 0, stream>>>(A, b3, cursor, bucket, dis, Wp4, B, n);

    // Layer 4 agg + W5 projection
    k_agg64z<<<ceil_div(n, 32), 256, 0, stream>>>(B, b4, W5, cursor, bucket, dis, zbuf, n);

    // Layer 5
    k_agg1<<<gn, NB, 0, stream>>>(zbuf, b5, cursor, bucket, dis, out, n);
}

// Round 9
// 215.129 us; speedup vs baseline: 3.1605x; 1.0534x over previous
//
#include <hip/hip_runtime.h>
#include <hip/hip_bf16.h>
#include <stdint.h>

// GCN 5-layer, N=100000, E=600000. bf16 pipeline, bucket-CSR, norm folded
// into GEMM epilogues. Round-9:
//  - k_l1mm: fused [3-wide agg (4 thr/node) + 3x128 expand + W2 MFMA] per
//    64-node tile (A buffer round-trip deleted).
//  - k_fillb unrolled x8 (8 independent atomic chains/thread).
//  - k_aggmm<128,64>, k_aggmm<64,64> tile-fused agg+GEMM as in round 8.

#define NB 256
#define CAP 64

typedef __attribute__((ext_vector_type(8))) short bf16x8;
typedef __attribute__((ext_vector_type(4))) float f32x4;

static __host__ __device__ inline int ceil_div(int a, int b) { return (a + b - 1) / b; }

__device__ inline ushort f32_to_bf16(float x) {   // RNE
    uint32_t u = __float_as_uint(x);
    uint32_t r = (u + 0x7fffu + ((u >> 16) & 1u)) >> 16;
    return (ushort)r;
}
__device__ inline float bf16_lo(uint32_t u) { return __uint_as_float(u << 16); }
__device__ inline float bf16_hi(uint32_t u) { return __uint_as_float(u & 0xffff0000u); }

// ---------------- init: zero cursor + pack weights ----------------

template <int K, int F>
__device__ inline void pack_one(const float* __restrict__ W, ushort* __restrict__ Wp, int id) {
    constexpr int KS = K / 32;
    int j = id & 7;
    int lane = (id >> 3) & 63;
    int ts = id >> 9;
    int s = ts % KS;
    int t = ts / KS;
    int k = s * 32 + ((lane >> 4) << 3) + j;
    int f = t * 16 + (lane & 15);
    Wp[id] = f32_to_bf16(W[k * F + f]);
}

__global__ void k_init(int* __restrict__ cursor, int n, int zero_blocks,
                       const float* __restrict__ W2, const float* __restrict__ W3,
                       const float* __restrict__ W4, ushort* __restrict__ Wp2,
                       ushort* __restrict__ Wp3, ushort* __restrict__ Wp4) {
    int b = blockIdx.x;
    if (b < zero_blocks) {
        int i = b * NB + threadIdx.x;
        if (i < n) cursor[i] = 0;
    } else {
        int id = (b - zero_blocks) * NB + threadIdx.x;
        if (id < 16384) pack_one<128, 128>(W2, Wp2, id);
        else if (id < 24576) pack_one<128, 64>(W3, Wp3, id - 16384);
        else if (id < 28672) pack_one<64, 64>(W4, Wp4, id - 24576);
    }
}

// ---------------- bucket CSR fill: x8 unrolled for atomic MLP ----------------

__global__ void k_fillb(const int* __restrict__ row, const int* __restrict__ col, int e,
                        int* __restrict__ cursor, int* __restrict__ bucket) {
    int T = (e + 7) >> 3;
    int t = blockIdx.x * NB + threadIdx.x;
    int i[8];
#pragma unroll
    for (int k = 0; k < 8; ++k) i[k] = t + k * T;
    if (i[7] < e) {
        int c[8], r[8], s[8];
#pragma unroll
        for (int k = 0; k < 8; ++k) { c[k] = col[i[k]]; r[k] = row[i[k]]; }
#pragma unroll
        for (int k = 0; k < 8; ++k) s[k] = atomicAdd(&cursor[c[k]], 1);
#pragma unroll
        for (int k = 0; k < 8; ++k) bucket[(size_t)c[k] * CAP + s[k]] = r[k];
    } else {
#pragma unroll
        for (int k = 0; k < 8; ++k) {
            if (i[k] < e) {
                int c = col[i[k]], r = row[i[k]];
                int s = atomicAdd(&cursor[c], 1);
                bucket[(size_t)c * CAP + s] = r;
            }
        }
    }
}

// dis = rsqrt(deg+1); xs = dis * x (stride-4 for aligned float4 gathers)
__global__ void k_dis(const int* __restrict__ cnt, const float* __restrict__ x,
                      float* __restrict__ dis, float4* __restrict__ xs4, int n) {
    int i = blockIdx.x * NB + threadIdx.x;
    if (i >= n) return;
    float d = rsqrtf((float)(cnt[i] + 1));
    dis[i] = d;
    xs4[i] = make_float4(d * x[3 * i], d * x[3 * i + 1], d * x[3 * i + 2], 0.f);
}

// ---------------- fused layer1 + W2 GEMM per 64-node tile ----------------
// Phase A: 4 threads/node sum xs4 over edges (strided), shfl-reduce, *dis.
// Phase B: 3->128 expand (W1+b1 in LDS) into padded bf16 tile.
// Phase C: 4 waves run 128->128 MFMA with dis epilogue -> Zout.

__global__ __launch_bounds__(256) void k_l1mm(const float4* __restrict__ xs4,
                                              const int* __restrict__ cnt,
                                              const int* __restrict__ bucket,
                                              const float* __restrict__ dis,
                                              const float* __restrict__ W1,
                                              const float* __restrict__ b1,
                                              const ushort* __restrict__ Wp2,
                                              ushort* __restrict__ Zout, int n) {
    __shared__ float w[512];          // W1 (384) + b1 (128)
    __shared__ float s_a[64][4];
    __shared__ ushort tileH[64][136]; // 128 + 8 pad
    for (int t = threadIdx.x; t < 512; t += 256)
        w[t] = (t < 384) ? W1[t] : b1[t - 384];

    int node0 = blockIdx.x * 64;
    int local = threadIdx.x >> 2;
    int sub = threadIdx.x & 3;
    int i = node0 + local;
    float a0 = 0.f, a1 = 0.f, a2 = 0.f;
    if (i < n) {
        if (sub == 0) {
            float4 self = xs4[i];
            a0 = self.x; a1 = self.y; a2 = self.z;
        }
        int deg = cnt[i];
        const int* bk = bucket + (size_t)i * CAP;
        for (int e = sub; e < deg; e += 4) {
            float4 v = xs4[bk[e]];
            a0 += v.x; a1 += v.y; a2 += v.z;
        }
    }
    a0 += __shfl_xor(a0, 1, 64); a1 += __shfl_xor(a1, 1, 64); a2 += __shfl_xor(a2, 1, 64);
    a0 += __shfl_xor(a0, 2, 64); a1 += __shfl_xor(a1, 2, 64); a2 += __shfl_xor(a2, 2, 64);
    if (sub == 0) {
        float d = (i < n) ? dis[i] : 0.f;
        s_a[local][0] = a0 * d;
        s_a[local][1] = a1 * d;
        s_a[local][2] = a2 * d;
    }
    __syncthreads();

    // expand: 64 nodes x 64 uint32 (2 packed bf16 feats) = 4096, 16/thread
#pragma unroll
    for (int it = 0; it < 16; ++it) {
        int id = it * 256 + threadIdx.x;
        int lc = id >> 6;
        int f = (id & 63) * 2;
        float h0 = s_a[lc][0], h1 = s_a[lc][1], h2 = s_a[lc][2];
        float v0 = fmaxf(h0 * w[f] + h1 * w[128 + f] + h2 * w[256 + f] + w[384 + f], 0.f);
        float v1 = fmaxf(h0 * w[f + 1] + h1 * w[128 + f + 1] + h2 * w[256 + f + 1] + w[384 + f + 1], 0.f);
        *(uint32_t*)&tileH[lc][f] = ((uint32_t)f32_to_bf16(v1) << 16) | (uint32_t)f32_to_bf16(v0);
    }
    __syncthreads();

    // MFMA 128 -> 128
    constexpr int KS = 4, FT = 8;
    int wid = threadIdx.x >> 6;
    int lane = threadIdx.x & 63;
    int m = lane & 15;
    int quad = lane >> 4;
    int tbase = wid * 16;
    bf16x8 a[KS];
#pragma unroll
    for (int s = 0; s < KS; ++s)
        a[s] = *(const bf16x8*)&tileH[tbase + m][s * 32 + quad * 8];
    float dsc[4];
#pragma unroll
    for (int r = 0; r < 4; ++r) {
        int node = node0 + tbase + quad * 4 + r;
        dsc[r] = (node < n) ? dis[node] : 0.f;
    }
    const bf16x8* bp = (const bf16x8*)Wp2;
#pragma unroll
    for (int t = 0; t < FT; ++t) {
        f32x4 acc = {0.f, 0.f, 0.f, 0.f};
#pragma unroll
        for (int s = 0; s < KS; ++s)
            acc = __builtin_amdgcn_mfma_f32_16x16x32_bf16(a[s], bp[(t * KS + s) * 64 + lane], acc, 0, 0, 0);
        int feat = t * 16 + m;
#pragma unroll
        for (int r = 0; r < 4; ++r) {
            int node = node0 + tbase + quad * 4 + r;
            if (node < n) Zout[(size_t)node * 128 + feat] = f32_to_bf16(acc[r] * dsc[r]);
        }
    }
}

// ---------------- aggregation primitives (pure sum gather, fp32 accum) ----------------

__device__ inline void add8(float (&a)[8], uint4 v) {
    a[0] += bf16_lo(v.x);
    a[1] += bf16_hi(v.x);
    a[2] += bf16_lo(v.y);
    a[3] += bf16_hi(v.y);
    a[4] += bf16_lo(v.z);
    a[5] += bf16_hi(v.z);
    a[6] += bf16_lo(v.w);
    a[7] += bf16_hi(v.w);
}

template <int L>
__device__ inline void agg_sum(float (&a)[8], const uint4* __restrict__ Zq,
                               const int* __restrict__ bk, int deg, int l, int i) {
    add8(a, Zq[(size_t)i * L + l]);   // self
    int e = 0;
    for (; e + 4 <= deg; e += 4) {
        int4 j4 = *(const int4*)(bk + e);
        uint4 v0 = Zq[(size_t)j4.x * L + l];
        uint4 v1 = Zq[(size_t)j4.y * L + l];
        uint4 v2 = Zq[(size_t)j4.z * L + l];
        uint4 v3 = Zq[(size_t)j4.w * L + l];
        add8(a, v0);
        add8(a, v1);
        add8(a, v2);
        add8(a, v3);
    }
    for (; e < deg; ++e) add8(a, Zq[(size_t)bk[e] * L + l]);
}

__device__ inline uint4 pack8s(const float (&a)[8], float d, const float* __restrict__ bias, int l) {
    float4 b0 = *(const float4*)&bias[8 * l];
    float4 b1 = *(const float4*)&bias[8 * l + 4];
    float r0 = fmaxf(a[0] * d + b0.x, 0.f), r1 = fmaxf(a[1] * d + b0.y, 0.f);
    float r2 = fmaxf(a[2] * d + b0.z, 0.f), r3 = fmaxf(a[3] * d + b0.w, 0.f);
    float r4 = fmaxf(a[4] * d + b1.x, 0.f), r5 = fmaxf(a[5] * d + b1.y, 0.f);
    float r6 = fmaxf(a[6] * d + b1.z, 0.f), r7 = fmaxf(a[7] * d + b1.w, 0.f);
    uint4 o;
    o.x = ((uint32_t)f32_to_bf16(r1) << 16) | (uint32_t)f32_to_bf16(r0);
    o.y = ((uint32_t)f32_to_bf16(r3) << 16) | (uint32_t)f32_to_bf16(r2);
    o.z = ((uint32_t)f32_to_bf16(r5) << 16) | (uint32_t)f32_to_bf16(r4);
    o.w = ((uint32_t)f32_to_bf16(r7) << 16) | (uint32_t)f32_to_bf16(r6);
    return o;
}

// ---------------- fused agg + GEMM per 64-node tile ----------------

template <int FIN, int FOUT>
__global__ __launch_bounds__(256) void k_aggmm(const ushort* __restrict__ Zin,
                                               const float* __restrict__ bias,
                                               const int* __restrict__ cnt,
                                               const int* __restrict__ bucket,
                                               const float* __restrict__ dis,
                                               const ushort* __restrict__ Wp,
                                               ushort* __restrict__ Zout, int n) {
    constexpr int L = FIN / 8;
    constexpr int GROUPS = 256 / L;
    constexpr int PASSES = 64 / GROUPS;
    __shared__ ushort tileA[64][FIN + 8];
    int node0 = blockIdx.x * 64;

    {
        int l = threadIdx.x & (L - 1);
        int g = threadIdx.x / L;
#pragma unroll
        for (int pass = 0; pass < PASSES; ++pass) {
            int local = pass * GROUPS + g;
            int i = node0 + local;
            if (i < n) {
                float a[8] = {0.f, 0.f, 0.f, 0.f, 0.f, 0.f, 0.f, 0.f};
                agg_sum<L>(a, (const uint4*)Zin, bucket + (size_t)i * CAP, cnt[i], l, i);
                *(uint4*)&tileA[local][l * 8] = pack8s(a, dis[i], bias, l);
            }
        }
    }
    __syncthreads();

    constexpr int KS = FIN / 32;
    constexpr int FT = FOUT / 16;
    int wid = threadIdx.x >> 6;
    int lane = threadIdx.x & 63;
    int m = lane & 15;
    int quad = lane >> 4;
    int tbase = wid * 16;
    bf16x8 a[KS];
#pragma unroll
    for (int s = 0; s < KS; ++s)
        a[s] = *(const bf16x8*)&tileA[tbase + m][s * 32 + quad * 8];
    float dsc[4];
#pragma unroll
    for (int r = 0; r < 4; ++r) {
        int node = node0 + tbase + quad * 4 + r;
        dsc[r] = (node < n) ? dis[node] : 0.f;
    }
    const bf16x8* bp = (const bf16x8*)Wp;
#pragma unroll
    for (int t = 0; t < FT; ++t) {
        f32x4 acc = {0.f, 0.f, 0.f, 0.f};
#pragma unroll
        for (int s = 0; s < KS; ++s)
            acc = __builtin_amdgcn_mfma_f32_16x16x32_bf16(a[s], bp[(t * KS + s) * 64 + lane], acc, 0, 0, 0);
        int feat = t * 16 + m;
#pragma unroll
        for (int r = 0; r < 4; ++r) {
            int node = node0 + tbase + quad * 4 + r;
            if (node < n) Zout[(size_t)node * FOUT + feat] = f32_to_bf16(acc[r] * dsc[r]);
        }
    }
}

// Layer-4 agg fused with 64->1 W5 projection; stores zbuf = dis_i * proj_i
__global__ __launch_bounds__(256) void k_agg64z(const ushort* __restrict__ Z,
                                                const float* __restrict__ bias,
                                                const float* __restrict__ W5,
                                                const int* __restrict__ cnt,
                                                const int* __restrict__ bucket,
                                                const float* __restrict__ dis,
                                                float* __restrict__ zbuf, int n) {
    int l = threadIdx.x & 7;
    int i = blockIdx.x * 32 + (threadIdx.x >> 3);
    if (i >= n) return;
    float a[8] = {0.f, 0.f, 0.f, 0.f, 0.f, 0.f, 0.f, 0.f};
    agg_sum<8>(a, (const uint4*)Z, bucket + (size_t)i * CAP, cnt[i], l, i);
    float d = dis[i];
    float4 b0 = *(const float4*)&bias[8 * l];
    float4 b1 = *(const float4*)&bias[8 * l + 4];
    float4 w0 = *(const float4*)&W5[8 * l];
    float4 w1 = *(const float4*)&W5[8 * l + 4];
    float p = fmaxf(a[0] * d + b0.x, 0.f) * w0.x + fmaxf(a[1] * d + b0.y, 0.f) * w0.y +
              fmaxf(a[2] * d + b0.z, 0.f) * w0.z + fmaxf(a[3] * d + b0.w, 0.f) * w0.w +
              fmaxf(a[4] * d + b1.x, 0.f) * w1.x + fmaxf(a[5] * d + b1.y, 0.f) * w1.y +
              fmaxf(a[6] * d + b1.z, 0.f) * w1.z + fmaxf(a[7] * d + b1.w, 0.f) * w1.w;
#pragma unroll
    for (int off = 4; off; off >>= 1) p += __shfl_xor(p, off, 64);
    if (l == 0) zbuf[i] = d * p;
}

// final: out_i = dis_i * (sum zbuf_j + zbuf_i) + b5
__global__ void k_agg1(const float* __restrict__ zbuf, const float* __restrict__ b5,
                       const int* __restrict__ cnt, const int* __restrict__ bucket,
                       const float* __restrict__ dis, float* __restrict__ out, int n) {
    int i = blockIdx.x * NB + threadIdx.x;
    if (i >= n) return;
    float acc = zbuf[i];
    int deg = cnt[i];
    const int* bk = bucket + (size_t)i * CAP;
    int e = 0;
    for (; e + 4 <= deg; e += 4) {
        int4 j4 = *(const int4*)(bk + e);
        acc += zbuf[j4.x] + zbuf[j4.y] + zbuf[j4.z] + zbuf[j4.w];
    }
    for (; e < deg; ++e) acc += zbuf[bk[e]];
    out[i] = dis[i] * acc + b5[0];
}

// ---------------- launch ----------------

static inline size_t align_up(size_t x) { return (x + 255) & ~(size_t)255; }

extern "C" void kernel_launch(void* const* d_in, const int* in_sizes, int n_in,
                              void* d_out, int out_size, void* d_ws, size_t ws_size,
                              hipStream_t stream) {
    const int n = in_sizes[0] / 3;   // 100000
    const int e = in_sizes[1] / 2;   // 600000

    const float* x   = (const float*)d_in[0];
    const int*   ei  = (const int*)d_in[1];
    const int*   row = ei;       // sources
    const int*   col = ei + e;   // targets
    const float* W1 = (const float*)d_in[2];  const float* b1 = (const float*)d_in[3];
    const float* W2 = (const float*)d_in[4];  const float* b2 = (const float*)d_in[5];
    const float* W3 = (const float*)d_in[6];  const float* b3 = (const float*)d_in[7];
    const float* W4 = (const float*)d_in[8];  const float* b4 = (const float*)d_in[9];
    const float* W5 = (const float*)d_in[10]; const float* b5 = (const float*)d_in[11];
    float* out = (float*)d_out;

    char* base = (char*)d_ws;
    size_t off = 0;
    auto alloc = [&](size_t bytes) { char* p = base + off; off = align_up(off + bytes); return p; };
    int*    cursor = (int*)alloc((size_t)n * 4);          // becomes degree
    float*  dis    = (float*)alloc((size_t)n * 4);
    float4* xs4    = (float4*)alloc((size_t)n * 16);
    int*    bucket = (int*)alloc((size_t)n * CAP * 4);    // 25.6 MB
    ushort* A      = (ushort*)alloc((size_t)n * 128 * 2);
    ushort* B      = (ushort*)alloc((size_t)n * 128 * 2);
    float*  zbuf   = (float*)alloc((size_t)n * 4);
    ushort* Wp2    = (ushort*)alloc(128 * 128 * 2);
    ushort* Wp3    = (ushort*)alloc(128 * 64 * 2);
    ushort* Wp4    = (ushort*)alloc(64 * 64 * 2);
    (void)ws_size;

    const int gn = ceil_div(n, NB);        // 391
    const int pack_blocks = ceil_div(16384 + 8192 + 4096, NB);  // 112

    // bucket CSR build
    k_init<<<gn + pack_blocks, NB, 0, stream>>>(cursor, n, gn, W2, W3, W4, Wp2, Wp3, Wp4);
    k_fillb<<<ceil_div(ceil_div(e, 8), NB), NB, 0, stream>>>(row, col, e, cursor, bucket);
    k_dis<<<gn, NB, 0, stream>>>(cursor, x, dis, xs4, n);

    // Layer 1 + Layer 2 GEMM (fused): B = dis (.) (relu(agg3(x)@W1+b1) @ W2)
    k_l1mm<<<ceil_div(n, 64), 256, 0, stream>>>(xs4, cursor, bucket, dis, W1, b1, Wp2, B, n);

    // Layer 2 agg + Layer 3 GEMM (fused): A = dis (.) (relu-agg(B,b2) @ W3)
    k_aggmm<128, 64><<<ceil_div(n, 64), 256, 0, stream>>>(B, b2, cursor, bucket, dis, Wp3, A, n);

    // Layer 3 agg + Layer 4 GEMM (fused): B = dis (.) (relu-agg(A,b3) @ W4)
    k_aggmm<64, 64><<<ceil_div(n, 64), 256, 0, stream>>>(A, b3, cursor, bucket, dis, Wp4, B, n);

    // Layer 4 agg + W5 projection
    k_agg64z<<<ceil_div(n, 32), 256, 0, stream>>>(B, b4, W5, cursor, bucket, dis, zbuf, n);

    // Layer 5
    k_agg1<<<gn, NB, 0, stream>>>(zbuf, b5, cursor, bucket, dis, out, n);
}